// Round 1
// baseline (731.884 us; speedup 1.0000x reference)
//
#include <hip/hip_runtime.h>
#include <math.h>

#define LLEN 256
#define NDIM 256
#define PDIM 128
#define NHEAD 8
#define HDIM 32
#define NPIX (LLEN*LLEN)

// ---- workspace layout (float offsets) ----
constexpr size_t OFF_Q     = 0;          // 65536
constexpr size_t OFF_K     = 65536;      // 65536
constexpr size_t OFF_V     = 131072;     // 65536
constexpr size_t OFF_CAT16 = 196608;     // 1048576  (L*L*16)
constexpr size_t OFF_A1    = 1245184;    // 524288   (L*L*8)
constexpr size_t OFF_ALPHA = 1769472;    // 524288
constexpr size_t OFF_AGG   = 2293760;    // 327680   (L*1280)
constexpr size_t OFF_ST16  = 2621440;    // 32
constexpr size_t OFF_ST9   = 2621504;    // 18 (padded)
constexpr size_t OFF_ST136 = 2621568;    // 272 (padded)
constexpr size_t OFF_WZT   = 2621952;    // 156672 (136*9*128)
// total ~2,778,624 floats = 11.1 MB

// ============ K1: q,k,v = x @ W^T ============
__global__ __launch_bounds__(256) void qkv_kernel(
    const float* __restrict__ x, const float* __restrict__ Wq,
    const float* __restrict__ Wk, const float* __restrict__ Wv,
    float* __restrict__ q, float* __restrict__ k, float* __restrict__ v){
  __shared__ __align__(16) float xs[NDIM];
  int i = blockIdx.x, m = blockIdx.y, t = threadIdx.x;
  xs[t] = x[i*NDIM + t];
  __syncthreads();
  const float* W = (m==0)?Wq:((m==1)?Wk:Wv);
  float* out = (m==0)?q:((m==1)?k:v);
  const float4* Wr = (const float4*)(W + (size_t)t*NDIM);
  float acc = 0.f;
  #pragma unroll 4
  for (int c4 = 0; c4 < NDIM/4; c4++){
    float4 w4 = Wr[c4];
    acc += w4.x*xs[c4*4] + w4.y*xs[c4*4+1] + w4.z*xs[c4*4+2] + w4.w*xs[c4*4+3];
  }
  out[i*NDIM + t] = acc;
}

// ============ K2: cat16 = [a_pair(8) | a_node(8)] per pixel ============
__global__ __launch_bounds__(256) void cat16_kernel(
    const float* __restrict__ z, const float* __restrict__ qb,
    const float* __restrict__ kb, const float* __restrict__ Wp2a,
    float* __restrict__ cat16){
  __shared__ float zs[32*128];
  __shared__ float wsm[8*128];
  __shared__ float qs[256];
  __shared__ float ks[32*256];
  int t = threadIdx.x;
  int pix0 = blockIdx.x * 32;
  int i = pix0 >> 8;
  int j0 = pix0 & 255;
  for (int idx = t; idx < 8*128; idx += 256) wsm[idx] = Wp2a[idx];
  qs[t] = qb[i*NDIM + t];
  for (int idx = t; idx < 32*128; idx += 256) zs[idx] = z[(size_t)pix0*128 + idx];
  for (int idx = t; idx < 32*256; idx += 256) ks[idx] = kb[(size_t)j0*NDIM + idx];
  __syncthreads();
  int p8 = t >> 3, h = t & 7;
  const float* zp = zs + p8*128;
  const float* wp = wsm + h*128;
  float ap = 0.f;
  #pragma unroll 8
  for (int p = 0; p < 128; p++) ap += zp[p]*wp[p];
  const float* qh = qs + h*32;
  const float* kh_ = ks + p8*256 + h*32;
  float an = 0.f;
  #pragma unroll
  for (int d = 0; d < HDIM; d++) an += qh[d]*kh_[d];
  an *= 0.17677669529663689f; // 1/sqrt(32)
  int pix = pix0 + p8;
  cat16[(size_t)pix*16 + h] = ap;
  cat16[(size_t)pix*16 + 8 + h] = an;
}

// ============ K3: per-channel instance-norm stats (mean, inv-std) ============
// channel c < Ca comes from A (stride Ca), else from B (stride Cb)
__global__ __launch_bounds__(256) void stats_kernel(
    const float* __restrict__ A, int Ca, const float* __restrict__ B, int Cb,
    float* __restrict__ st){
  int c = blockIdx.x, t = threadIdx.x;
  int C = Ca + Cb;
  const float* src; int stride, off;
  if (c < Ca){ src = A; stride = Ca; off = c; }
  else       { src = B; stride = Cb; off = c - Ca; }
  float s = 0.f, s2 = 0.f;
  for (int base = 0; base < NPIX; base += 256){
    float vv = src[(size_t)(base + t)*stride + off];
    s += vv; s2 += vv*vv;
  }
  __shared__ float red[8];
  int lane = t & 63, wv = t >> 6;
  #pragma unroll
  for (int o = 32; o > 0; o >>= 1){ s += __shfl_down(s, o); s2 += __shfl_down(s2, o); }
  if (lane == 0){ red[wv] = s; red[4+wv] = s2; }
  __syncthreads();
  if (t == 0){
    float S  = red[0]+red[1]+red[2]+red[3];
    float S2 = red[4]+red[5]+red[6]+red[7];
    float m = S * (1.f/NPIX);
    float var = S2 * (1.f/NPIX) - m*m;
    st[c] = m;
    st[C + c] = rsqrtf(var + 1e-5f);
  }
}

// ============ K4/K6: small conv 3x3 (CIN -> COUT) with fused inorm + lrelu ====
template<int CIN, int COUT>
__global__ __launch_bounds__(256) void conv_small_kernel(
    const float* __restrict__ A, int Ca, const float* __restrict__ B, int Cb,
    const float* __restrict__ st, const float* __restrict__ w,
    const float* __restrict__ bias, float* __restrict__ out){
  __shared__ float xn[3][256][CIN];
  __shared__ float wsm[COUT*CIN*9];
  __shared__ float ms[CIN], isd[CIN], bs[COUT];
  int i = blockIdx.x, t = threadIdx.x;
  if (t < CIN){ ms[t] = st[t]; isd[t] = st[CIN + t]; }
  if (t < COUT) bs[t] = bias[t];
  for (int idx = t; idx < COUT*CIN*9; idx += 256) wsm[idx] = w[idx];
  __syncthreads();
  for (int r = 0; r < 3; r++){
    int row = i - 1 + r;
    for (int idx = t; idx < 256*CIN; idx += 256){
      int col = idx / CIN, c = idx - col*CIN;
      float vv = 0.f;
      if (row >= 0 && row < 256){
        size_t pix = (size_t)row*256 + col;
        float raw = (c < Ca) ? A[pix*Ca + c] : B[pix*Cb + (c - Ca)];
        vv = (raw - ms[c]) * isd[c];
      }
      xn[r][col][c] = vv;
    }
  }
  __syncthreads();
  int j = t;
  float acc[COUT];
  #pragma unroll
  for (int o = 0; o < COUT; o++) acc[o] = bs[o];
  #pragma unroll
  for (int kh = 0; kh < 3; kh++){
    #pragma unroll
    for (int kw = 0; kw < 3; kw++){
      int jj = j + kw - 1;
      if (jj < 0 || jj > 255) continue;
      float vreg[CIN];
      #pragma unroll
      for (int c = 0; c < CIN; c++) vreg[c] = xn[kh][jj][c];
      #pragma unroll
      for (int o = 0; o < COUT; o++){
        float a = 0.f;
        #pragma unroll
        for (int c = 0; c < CIN; c++) a += vreg[c]*wsm[((o*CIN + c)*3 + kh)*3 + kw];
        acc[o] += a;
      }
    }
  }
  #pragma unroll
  for (int o = 0; o < COUT; o++){
    float vv = acc[o];
    out[((size_t)(i*256 + j))*COUT + o] = (vv >= 0.f) ? vv : 0.01f*vv;
  }
}

// ============ K7: node_from_pair + node_from_node -> agg (L,1280) ============
__global__ __launch_bounds__(256) void agg_kernel(
    const float* __restrict__ alpha, const float* __restrict__ z,
    const float* __restrict__ v, float* __restrict__ agg){
  __shared__ float as[256*8];
  int i = blockIdx.x, t = threadIdx.x;
  for (int idx = t; idx < 2048; idx += 256) as[idx] = alpha[(size_t)i*2048 + idx];
  __syncthreads();
  // node_from_pair: out[h*128+p] = sum_j alpha[j,h]*z[i,j,p]
  int p = t & 127, hh = t >> 7; // hh in {0,1}, 4 heads each
  const float* zrow = z + (size_t)i*(256*128);
  float a0=0.f, a1=0.f, a2=0.f, a3=0.f;
  for (int j = 0; j < 256; j++){
    float zv = zrow[j*128 + p];
    const float* ar = as + j*8 + hh*4;
    a0 += ar[0]*zv; a1 += ar[1]*zv; a2 += ar[2]*zv; a3 += ar[3]*zv;
  }
  size_t ob = (size_t)i*1280;
  agg[ob + (hh*4+0)*128 + p] = a0;
  agg[ob + (hh*4+1)*128 + p] = a1;
  agg[ob + (hh*4+2)*128 + p] = a2;
  agg[ob + (hh*4+3)*128 + p] = a3;
  // node_from_node: out[1024 + h*32+d] = sum_j alpha[j,h]*v[j, h*32+d]
  int h = t >> 5;
  float an = 0.f;
  for (int j = 0; j < 256; j++) an += as[j*8 + h]*v[(size_t)j*256 + t];
  agg[ob + 1024 + t] = an;
}

// ============ K8: out_transform: LN -> lin1 -> LN -> lrelu -> lin2 -> +x -> LN
__device__ inline void block_reduce2(float& s, float& s2, float* red){
  int t = threadIdx.x;
  int lane = t & 63, wv = t >> 6;
  #pragma unroll
  for (int o = 32; o > 0; o >>= 1){ s += __shfl_down(s, o); s2 += __shfl_down(s2, o); }
  __syncthreads();
  if (lane == 0){ red[wv] = s; red[4+wv] = s2; }
  __syncthreads();
  s  = red[0]+red[1]+red[2]+red[3];
  s2 = red[4]+red[5]+red[6]+red[7];
}

__global__ __launch_bounds__(256) void out_kernel(
    const float* __restrict__ agg, const float* __restrict__ x,
    const float* __restrict__ ln1_g, const float* __restrict__ ln1_b,
    const float* __restrict__ lin1_w, const float* __restrict__ lin1_b,
    const float* __restrict__ ln2_g, const float* __restrict__ ln2_b,
    const float* __restrict__ lin2_w, const float* __restrict__ lin2_b,
    const float* __restrict__ lnf_g, const float* __restrict__ lnf_b,
    float* __restrict__ xout){
  __shared__ __align__(16) float h1[1280];
  __shared__ __align__(16) float h2[512];
  __shared__ float red[8];
  int i = blockIdx.x, t = threadIdx.x;
  float vals[5]; float s = 0.f, s2 = 0.f;
  #pragma unroll
  for (int r = 0; r < 5; r++){
    float vv = agg[(size_t)i*1280 + r*256 + t];
    vals[r] = vv; s += vv; s2 += vv*vv;
  }
  block_reduce2(s, s2, red);
  float m = s*(1.f/1280.f);
  float istd = rsqrtf(s2*(1.f/1280.f) - m*m + 1e-5f);
  #pragma unroll
  for (int r = 0; r < 5; r++){
    int kk = r*256 + t;
    h1[kk] = (vals[r] - m)*istd*ln1_g[kk] + ln1_b[kk];
  }
  __syncthreads();
  float y0 = lin1_b[t], y1 = lin1_b[t + 256];
  {
    const float4* w0 = (const float4*)(lin1_w + (size_t)t*1280);
    const float4* w1 = (const float4*)(lin1_w + (size_t)(t + 256)*1280);
    const float4* hv = (const float4*)h1;
    for (int kk = 0; kk < 320; kk++){
      float4 hh = hv[kk];
      float4 a = w0[kk]; y0 += a.x*hh.x + a.y*hh.y + a.z*hh.z + a.w*hh.w;
      float4 b = w1[kk]; y1 += b.x*hh.x + b.y*hh.y + b.z*hh.z + b.w*hh.w;
    }
  }
  s = y0 + y1; s2 = y0*y0 + y1*y1;
  block_reduce2(s, s2, red);
  m = s*(1.f/512.f); istd = rsqrtf(s2*(1.f/512.f) - m*m + 1e-5f);
  float z0 = (y0 - m)*istd*ln2_g[t] + ln2_b[t];
  float z1 = (y1 - m)*istd*ln2_g[t+256] + ln2_b[t+256];
  h2[t]     = (z0 >= 0.f) ? z0 : 0.01f*z0;
  h2[t+256] = (z1 >= 0.f) ? z1 : 0.01f*z1;
  __syncthreads();
  float y = lin2_b[t];
  {
    const float4* w2 = (const float4*)(lin2_w + (size_t)t*512);
    const float4* hv = (const float4*)h2;
    for (int kk = 0; kk < 128; kk++){
      float4 a = w2[kk]; float4 hh = hv[kk];
      y += a.x*hh.x + a.y*hh.y + a.z*hh.z + a.w*hh.w;
    }
  }
  float xr = x[i*256 + t] + y;
  s = xr; s2 = xr*xr;
  block_reduce2(s, s2, red);
  m = s*(1.f/256.f); istd = rsqrtf(s2*(1.f/256.f) - m*m + 1e-5f);
  xout[i*256 + t] = (xr - m)*istd*lnf_g[t] + lnf_b[t];
}

// ============ K10: transpose conv_z weights to [c*9+k][o] (coalesced) ========
__global__ __launch_bounds__(256) void wzt_kernel(const float* __restrict__ w,
                                                  float* __restrict__ wt){
  int idx = blockIdx.x*256 + threadIdx.x;
  if (idx >= 128*136*9) return;
  int o = idx / (136*9);
  int r = idx - o*(136*9);   // c*9 + kh*3 + kw
  wt[(size_t)r*128 + o] = w[idx];
}

// ============ K11: conv_z 3x3, 136->128, fused inorm + lrelu ================
__global__ __launch_bounds__(256) void conv_z_kernel(
    const float* __restrict__ z, const float* __restrict__ alpha,
    const float* __restrict__ st, const float* __restrict__ wt,
    const float* __restrict__ bias, float* __restrict__ out){
  __shared__ float xn[3][34][136];   // rows i-1..i+1, cols j0-1..j0+32
  __shared__ float ms[136], isd[136];
  int t = threadIdx.x, bi = blockIdx.x;
  int i = bi >> 3;
  int j0 = (bi & 7)*32;
  if (t < 136){ ms[t] = st[t]; isd[t] = st[136 + t]; }
  __syncthreads();
  for (int idx = t; idx < 3*34*136; idx += 256){
    int r = idx / (34*136);
    int rem = idx - r*(34*136);
    int col = rem / 136;
    int c = rem - col*136;
    int row = i - 1 + r;
    int gj = j0 - 1 + col;
    float vv = 0.f;
    if (row >= 0 && row < 256 && gj >= 0 && gj < 256){
      size_t pix = (size_t)row*256 + gj;
      float raw = (c < 128) ? z[pix*128 + c] : alpha[pix*8 + (c - 128)];
      vv = (raw - ms[c]) * isd[c];
    }
    (&xn[0][0][0])[idx] = vv;
  }
  __syncthreads();
  int og = t & 31;   // 4 out-channels each: o = og*4..og*4+3
  int pg = t >> 5;   // 4 pixels each:      j = j0 + pg*4 .. +3
  float acc[4][4];
  #pragma unroll
  for (int a = 0; a < 4; a++)
    #pragma unroll
    for (int b = 0; b < 4; b++) acc[a][b] = 0.f;
  for (int c = 0; c < 136; c++){
    #pragma unroll
    for (int kh = 0; kh < 3; kh++){
      #pragma unroll
      for (int kw = 0; kw < 3; kw++){
        float4 w4 = *(const float4*)(wt + (size_t)(c*9 + kh*3 + kw)*128 + og*4);
        float pv0 = xn[kh][pg*4 + 0 + kw][c];
        float pv1 = xn[kh][pg*4 + 1 + kw][c];
        float pv2 = xn[kh][pg*4 + 2 + kw][c];
        float pv3 = xn[kh][pg*4 + 3 + kw][c];
        acc[0][0] += pv0*w4.x; acc[0][1] += pv0*w4.y; acc[0][2] += pv0*w4.z; acc[0][3] += pv0*w4.w;
        acc[1][0] += pv1*w4.x; acc[1][1] += pv1*w4.y; acc[1][2] += pv1*w4.z; acc[1][3] += pv1*w4.w;
        acc[2][0] += pv2*w4.x; acc[2][1] += pv2*w4.y; acc[2][2] += pv2*w4.z; acc[2][3] += pv2*w4.w;
        acc[3][0] += pv3*w4.x; acc[3][1] += pv3*w4.y; acc[3][2] += pv3*w4.z; acc[3][3] += pv3*w4.w;
      }
    }
  }
  float4 b4 = *(const float4*)(bias + og*4);
  #pragma unroll
  for (int pp = 0; pp < 4; pp++){
    int j = j0 + pg*4 + pp;
    float4 ov;
    ov.x = acc[pp][0] + b4.x;
    ov.y = acc[pp][1] + b4.y;
    ov.z = acc[pp][2] + b4.z;
    ov.w = acc[pp][3] + b4.w;
    ov.x = (ov.x >= 0.f) ? ov.x : 0.01f*ov.x;
    ov.y = (ov.y >= 0.f) ? ov.y : 0.01f*ov.y;
    ov.z = (ov.z >= 0.f) ? ov.z : 0.01f*ov.z;
    ov.w = (ov.w >= 0.f) ? ov.w : 0.01f*ov.w;
    *(float4*)(out + ((size_t)(i*256 + j))*128 + og*4) = ov;
  }
}

extern "C" void kernel_launch(void* const* d_in, const int* in_sizes, int n_in,
                              void* d_out, int out_size, void* d_ws, size_t ws_size,
                              hipStream_t stream){
  const float* x        = (const float*)d_in[0];
  const float* z        = (const float*)d_in[1];
  const float* plddt    = (const float*)d_in[2];
  const float* Wq       = (const float*)d_in[3];
  const float* Wk       = (const float*)d_in[4];
  const float* Wv       = (const float*)d_in[5];
  const float* Wp2a     = (const float*)d_in[6];
  const float* conv_a_w = (const float*)d_in[7];
  const float* conv_a_b = (const float*)d_in[8];
  const float* conv_p_w = (const float*)d_in[9];
  const float* conv_p_b = (const float*)d_in[10];
  const float* ln1_g    = (const float*)d_in[11];
  const float* ln1_b    = (const float*)d_in[12];
  const float* lin1_w   = (const float*)d_in[13];
  const float* lin1_b   = (const float*)d_in[14];
  const float* ln2_g    = (const float*)d_in[15];
  const float* ln2_b    = (const float*)d_in[16];
  const float* lin2_w   = (const float*)d_in[17];
  const float* lin2_b   = (const float*)d_in[18];
  const float* lnf_g    = (const float*)d_in[19];
  const float* lnf_b    = (const float*)d_in[20];
  const float* conv_z_w = (const float*)d_in[21];
  const float* conv_z_b = (const float*)d_in[22];

  float* ws    = (float*)d_ws;
  float* q     = ws + OFF_Q;
  float* k     = ws + OFF_K;
  float* v     = ws + OFF_V;
  float* cat16 = ws + OFF_CAT16;
  float* a1    = ws + OFF_A1;
  float* alpha = ws + OFF_ALPHA;
  float* agg   = ws + OFF_AGG;
  float* st16  = ws + OFF_ST16;
  float* st9   = ws + OFF_ST9;
  float* st136 = ws + OFF_ST136;
  float* wzt   = ws + OFF_WZT;

  float* xout = (float*)d_out;
  float* zout = (float*)d_out + 65536;

  qkv_kernel<<<dim3(256,3), 256, 0, stream>>>(x, Wq, Wk, Wv, q, k, v);
  cat16_kernel<<<2048, 256, 0, stream>>>(z, q, k, Wp2a, cat16);
  stats_kernel<<<16, 256, 0, stream>>>(cat16, 16, (const float*)nullptr, 0, st16);
  conv_small_kernel<16,8><<<256, 256, 0, stream>>>(cat16, 16, (const float*)nullptr, 0,
                                                   st16, conv_a_w, conv_a_b, a1);
  stats_kernel<<<9, 256, 0, stream>>>(a1, 8, plddt, 1, st9);
  conv_small_kernel<9,8><<<256, 256, 0, stream>>>(a1, 8, plddt, 1,
                                                  st9, conv_p_w, conv_p_b, alpha);
  agg_kernel<<<256, 256, 0, stream>>>(alpha, z, v, agg);
  out_kernel<<<256, 256, 0, stream>>>(agg, x, ln1_g, ln1_b, lin1_w, lin1_b,
                                      ln2_g, ln2_b, lin2_w, lin2_b, lnf_g, lnf_b, xout);
  stats_kernel<<<136, 256, 0, stream>>>(z, 128, alpha, 8, st136);
  wzt_kernel<<<612, 256, 0, stream>>>(conv_z_w, wzt);
  conv_z_kernel<<<2048, 256, 0, stream>>>(z, alpha, st136, wzt, conv_z_b, zout);
}

// Round 4
// 530.963 us; speedup vs baseline: 1.3784x; 1.3784x over previous
//
#include <hip/hip_runtime.h>
#include <math.h>

#define LLEN 256
#define NDIM 256
#define PDIM 128
#define NHEAD 8
#define HDIM 32
#define NPIX (LLEN*LLEN)

typedef __bf16 bf16x8 __attribute__((ext_vector_type(8)));
typedef float f32x4 __attribute__((ext_vector_type(4)));

// ---- workspace layout (float offsets) ----
constexpr size_t OFF_Q     = 0;          // 65536
constexpr size_t OFF_K     = 65536;      // 65536
constexpr size_t OFF_V     = 131072;     // 65536
constexpr size_t OFF_CAT16 = 196608;     // 1048576  (L*L*16)
constexpr size_t OFF_A1    = 1245184;    // 524288   (L*L*8)
constexpr size_t OFF_ALPHA = 1769472;    // 524288
constexpr size_t OFF_AGG   = 2293760;    // 327680   (L*1280)
constexpr size_t OFF_ST16  = 2621440;    // 32
constexpr size_t OFF_ST9   = 2621504;    // 18 (padded)
constexpr size_t OFF_ST136 = 2621568;    // 272 (padded)
constexpr size_t OFF_WZB   = 2621952;    // 184320 bf16 = 92160 floats
constexpr size_t OFF_Y     = 2778624;    // 131072 (256*512)
// total ~2,909,696 floats = 11.6 MB

__device__ inline unsigned short f2b(float x){
  union { float f; unsigned u; } a; a.f = x;
  unsigned r = a.u + 0x7fffu + ((a.u >> 16) & 1u);
  return (unsigned short)(r >> 16);
}

// ============ K1: q,k,v = x @ W^T  (8 rows per block, weight-quad reuse) =====
__global__ __launch_bounds__(256) void qkv_kernel(
    const float* __restrict__ x, const float* __restrict__ Wq,
    const float* __restrict__ Wk, const float* __restrict__ Wv,
    float* __restrict__ q, float* __restrict__ k, float* __restrict__ v){
  __shared__ __align__(16) float xs[8][256];
  int t = threadIdx.x;
  int i0 = blockIdx.x * 8;
  int m = blockIdx.y;
  const float* W = (m==0)?Wq:((m==1)?Wk:Wv);
  float* out = (m==0)?q:((m==1)?k:v);
  for (int idx = t; idx < 2048; idx += 256)
    xs[idx>>8][idx&255] = x[(size_t)i0*256 + idx];
  __syncthreads();
  float acc[8];
  #pragma unroll
  for (int r = 0; r < 8; r++) acc[r] = 0.f;
  const float4* wr = (const float4*)(W + (size_t)t*256);
  for (int kk = 0; kk < 64; ++kk){
    float4 w4 = wr[kk];
    #pragma unroll
    for (int r = 0; r < 8; r++){
      float4 xv = ((const float4*)xs[r])[kk];
      acc[r] += w4.x*xv.x + w4.y*xv.y + w4.z*xv.z + w4.w*xv.w;
    }
  }
  #pragma unroll
  for (int r = 0; r < 8; r++) out[(size_t)(i0+r)*256 + t] = acc[r];
}

// ============ K2: cat16 = [a_pair(8) | a_node(8)] per pixel ============
__global__ __launch_bounds__(256) void cat16_kernel(
    const float* __restrict__ z, const float* __restrict__ qb,
    const float* __restrict__ kb, const float* __restrict__ Wp2a,
    float* __restrict__ cat16){
  __shared__ float zs[32*128];
  __shared__ float wsm[8*128];
  __shared__ float qs[256];
  __shared__ float ks[32*256];
  int t = threadIdx.x;
  int pix0 = blockIdx.x * 32;
  int i = pix0 >> 8;
  int j0 = pix0 & 255;
  for (int idx = t; idx < 8*128; idx += 256) wsm[idx] = Wp2a[idx];
  qs[t] = qb[i*NDIM + t];
  for (int idx = t; idx < 32*128; idx += 256) zs[idx] = z[(size_t)pix0*128 + idx];
  for (int idx = t; idx < 32*256; idx += 256) ks[idx] = kb[(size_t)j0*NDIM + idx];
  __syncthreads();
  int p8 = t >> 3, h = t & 7;
  const float* zp = zs + p8*128;
  const float* wp = wsm + h*128;
  float ap = 0.f;
  #pragma unroll 8
  for (int p = 0; p < 128; p++) ap += zp[p]*wp[p];
  const float* qh = qs + h*32;
  const float* kh_ = ks + p8*256 + h*32;
  float an = 0.f;
  #pragma unroll
  for (int d = 0; d < HDIM; d++) an += qh[d]*kh_[d];
  an *= 0.17677669529663689f; // 1/sqrt(32)
  int pix = pix0 + p8;
  cat16[(size_t)pix*16 + h] = ap;
  cat16[(size_t)pix*16 + 8 + h] = an;
}

// ============ K3: per-channel instance-norm stats (mean, inv-std) ============
__global__ __launch_bounds__(256) void stats_kernel(
    const float* __restrict__ A, int Ca, const float* __restrict__ B, int Cb,
    float* __restrict__ st){
  int c = blockIdx.x, t = threadIdx.x;
  int C = Ca + Cb;
  const float* src; int stride, off;
  if (c < Ca){ src = A; stride = Ca; off = c; }
  else       { src = B; stride = Cb; off = c - Ca; }
  float s = 0.f, s2 = 0.f;
  for (int base = 0; base < NPIX; base += 256){
    float vv = src[(size_t)(base + t)*stride + off];
    s += vv; s2 += vv*vv;
  }
  __shared__ float red[8];
  int lane = t & 63, wv = t >> 6;
  #pragma unroll
  for (int o = 32; o > 0; o >>= 1){ s += __shfl_down(s, o); s2 += __shfl_down(s2, o); }
  if (lane == 0){ red[wv] = s; red[4+wv] = s2; }
  __syncthreads();
  if (t == 0){
    float S  = red[0]+red[1]+red[2]+red[3];
    float S2 = red[4]+red[5]+red[6]+red[7];
    float m = S * (1.f/NPIX);
    float var = S2 * (1.f/NPIX) - m*m;
    st[c] = m;
    st[C + c] = rsqrtf(var + 1e-5f);
  }
}

// ============ K4/K6: small conv 3x3 (CIN -> COUT) fused inorm + lrelu ====
template<int CIN, int COUT>
__global__ __launch_bounds__(256) void conv_small_kernel(
    const float* __restrict__ A, int Ca, const float* __restrict__ B, int Cb,
    const float* __restrict__ st, const float* __restrict__ w,
    const float* __restrict__ bias, float* __restrict__ out){
  __shared__ float xn[3][256][CIN];
  __shared__ float wsm[COUT*CIN*9];
  __shared__ float ms[CIN], isd[CIN], bs[COUT];
  int i = blockIdx.x, t = threadIdx.x;
  if (t < CIN){ ms[t] = st[t]; isd[t] = st[CIN + t]; }
  if (t < COUT) bs[t] = bias[t];
  for (int idx = t; idx < COUT*CIN*9; idx += 256) wsm[idx] = w[idx];
  __syncthreads();
  for (int r = 0; r < 3; r++){
    int row = i - 1 + r;
    for (int idx = t; idx < 256*CIN; idx += 256){
      int col = idx / CIN, c = idx - col*CIN;
      float vv = 0.f;
      if (row >= 0 && row < 256){
        size_t pix = (size_t)row*256 + col;
        float raw = (c < Ca) ? A[pix*Ca + c] : B[pix*Cb + (c - Ca)];
        vv = (raw - ms[c]) * isd[c];
      }
      xn[r][col][c] = vv;
    }
  }
  __syncthreads();
  int j = t;
  float acc[COUT];
  #pragma unroll
  for (int o = 0; o < COUT; o++) acc[o] = bs[o];
  #pragma unroll
  for (int kh = 0; kh < 3; kh++){
    #pragma unroll
    for (int kw = 0; kw < 3; kw++){
      int jj = j + kw - 1;
      if (jj < 0 || jj > 255) continue;
      float vreg[CIN];
      #pragma unroll
      for (int c = 0; c < CIN; c++) vreg[c] = xn[kh][jj][c];
      #pragma unroll
      for (int o = 0; o < COUT; o++){
        float a = 0.f;
        #pragma unroll
        for (int c = 0; c < CIN; c++) a += vreg[c]*wsm[((o*CIN + c)*3 + kh)*3 + kw];
        acc[o] += a;
      }
    }
  }
  #pragma unroll
  for (int o = 0; o < COUT; o++){
    float vv = acc[o];
    out[((size_t)(i*256 + j))*COUT + o] = (vv >= 0.f) ? vv : 0.01f*vv;
  }
}

// ============ K7: node_from_pair + node_from_node -> agg (L,1280) ============
__global__ __launch_bounds__(256) void agg_kernel(
    const float* __restrict__ alpha, const float* __restrict__ z,
    const float* __restrict__ v, float* __restrict__ agg){
  __shared__ float as[256*8];
  int i = blockIdx.x, t = threadIdx.x;
  for (int idx = t; idx < 2048; idx += 256) as[idx] = alpha[(size_t)i*2048 + idx];
  __syncthreads();
  int p = t & 127, hh = t >> 7;
  const float* zrow = z + (size_t)i*(256*128);
  float a0=0.f, a1=0.f, a2=0.f, a3=0.f;
  for (int j = 0; j < 256; j++){
    float zv = zrow[j*128 + p];
    const float* ar = as + j*8 + hh*4;
    a0 += ar[0]*zv; a1 += ar[1]*zv; a2 += ar[2]*zv; a3 += ar[3]*zv;
  }
  size_t ob = (size_t)i*1280;
  agg[ob + (hh*4+0)*128 + p] = a0;
  agg[ob + (hh*4+1)*128 + p] = a1;
  agg[ob + (hh*4+2)*128 + p] = a2;
  agg[ob + (hh*4+3)*128 + p] = a3;
  int h = t >> 5;
  float an = 0.f;
  for (int j = 0; j < 256; j++) an += as[j*8 + h]*v[(size_t)j*256 + t];
  agg[ob + 1024 + t] = an;
}

// ============ shared reduction helper ============
__device__ inline void block_reduce2(float& s, float& s2, float* red){
  int t = threadIdx.x;
  int lane = t & 63, wv = t >> 6;
  #pragma unroll
  for (int o = 32; o > 0; o >>= 1){ s += __shfl_down(s, o); s2 += __shfl_down(s2, o); }
  __syncthreads();
  if (lane == 0){ red[wv] = s; red[4+wv] = s2; }
  __syncthreads();
  s  = red[0]+red[1]+red[2]+red[3];
  s2 = red[4]+red[5]+red[6]+red[7];
}

// ============ K8a: LN1 + lin1 (8 rows x 128 outs per block) ============
__global__ __launch_bounds__(256) void outA_kernel(
    const float* __restrict__ agg,
    const float* __restrict__ ln1_g, const float* __restrict__ ln1_b,
    const float* __restrict__ lin1_w, const float* __restrict__ lin1_b,
    float* __restrict__ y){
  __shared__ __align__(16) float h1[8][1280];
  __shared__ float red[8];
  int t = threadIdx.x;
  int rb = blockIdx.x >> 2, ob = blockIdx.x & 3;
  for (int r = 0; r < 8; ++r){
    int i = rb*8 + r;
    float v[5], s = 0.f, s2 = 0.f;
    #pragma unroll
    for (int qq = 0; qq < 5; ++qq){
      v[qq] = agg[(size_t)i*1280 + qq*256 + t];
      s += v[qq]; s2 += v[qq]*v[qq];
    }
    block_reduce2(s, s2, red);
    float m = s*(1.f/1280.f), istd = rsqrtf(s2*(1.f/1280.f) - m*m + 1e-5f);
    #pragma unroll
    for (int qq = 0; qq < 5; ++qq){
      int kk = qq*256 + t;
      h1[r][kk] = (v[qq] - m)*istd*ln1_g[kk] + ln1_b[kk];
    }
  }
  __syncthreads();
  int o = ob*128 + (t & 127);
  int half = t >> 7;
  float a0=0.f, a1=0.f, a2=0.f, a3=0.f;
  const float4* wr = (const float4*)(lin1_w + (size_t)o*1280);
  const float4* r0 = (const float4*)h1[half*4+0];
  const float4* r1 = (const float4*)h1[half*4+1];
  const float4* r2 = (const float4*)h1[half*4+2];
  const float4* r3 = (const float4*)h1[half*4+3];
  for (int kk = 0; kk < 320; ++kk){
    float4 w4 = wr[kk];
    float4 x0 = r0[kk]; a0 += w4.x*x0.x + w4.y*x0.y + w4.z*x0.z + w4.w*x0.w;
    float4 x1 = r1[kk]; a1 += w4.x*x1.x + w4.y*x1.y + w4.z*x1.z + w4.w*x1.w;
    float4 x2 = r2[kk]; a2 += w4.x*x2.x + w4.y*x2.y + w4.z*x2.z + w4.w*x2.w;
    float4 x3 = r3[kk]; a3 += w4.x*x3.x + w4.y*x3.y + w4.z*x3.z + w4.w*x3.w;
  }
  int i0 = rb*8 + half*4;
  float bb = lin1_b[o];
  y[(size_t)(i0+0)*512 + o] = a0 + bb;
  y[(size_t)(i0+1)*512 + o] = a1 + bb;
  y[(size_t)(i0+2)*512 + o] = a2 + bb;
  y[(size_t)(i0+3)*512 + o] = a3 + bb;
}

// ============ K8b: LN2 + lrelu + lin2 + residual + LNf (8 rows/block) ========
__global__ __launch_bounds__(256) void outB_kernel(
    const float* __restrict__ y, const float* __restrict__ x,
    const float* __restrict__ ln2_g, const float* __restrict__ ln2_b,
    const float* __restrict__ lin2_w, const float* __restrict__ lin2_b,
    const float* __restrict__ lnf_g, const float* __restrict__ lnf_b,
    float* __restrict__ xout){
  __shared__ __align__(16) float h2[8][512];
  __shared__ float red[8];
  int t = threadIdx.x;
  int rb = blockIdx.x;
  for (int r = 0; r < 8; ++r){
    int i = rb*8 + r;
    float y0 = y[(size_t)i*512 + t], y1 = y[(size_t)i*512 + 256 + t];
    float s = y0 + y1, s2 = y0*y0 + y1*y1;
    block_reduce2(s, s2, red);
    float m = s*(1.f/512.f), istd = rsqrtf(s2*(1.f/512.f) - m*m + 1e-5f);
    float z0 = (y0 - m)*istd*ln2_g[t] + ln2_b[t];
    float z1 = (y1 - m)*istd*ln2_g[t+256] + ln2_b[t+256];
    h2[r][t]     = (z0 >= 0.f) ? z0 : 0.01f*z0;
    h2[r][t+256] = (z1 >= 0.f) ? z1 : 0.01f*z1;
  }
  __syncthreads();
  float acc[8];
  #pragma unroll
  for (int r = 0; r < 8; ++r) acc[r] = 0.f;
  const float4* wr = (const float4*)(lin2_w + (size_t)t*512);
  for (int kk = 0; kk < 128; ++kk){
    float4 w4 = wr[kk];
    #pragma unroll
    for (int r = 0; r < 8; ++r){
      float4 h = ((const float4*)h2[r])[kk];
      acc[r] += w4.x*h.x + w4.y*h.y + w4.z*h.z + w4.w*h.w;
    }
  }
  float bb = lin2_b[t];
  for (int r = 0; r < 8; ++r){
    int i = rb*8 + r;
    float xr = x[(size_t)i*256 + t] + acc[r] + bb;
    float s = xr, s2 = xr*xr;
    block_reduce2(s, s2, red);
    float m = s*(1.f/256.f), istd = rsqrtf(s2*(1.f/256.f) - m*m + 1e-5f);
    xout[(size_t)i*256 + t] = (xr - m)*istd*lnf_g[t] + lnf_b[t];
  }
}

// ============ K10: conv_z weights -> bf16 [o][tap][160] (c padded w/ zeros) ==
__global__ __launch_bounds__(256) void wz_prep(const float* __restrict__ w,
                                               unsigned short* __restrict__ wzb){
  int idx = blockIdx.x*256 + threadIdx.x;
  if (idx >= 128*1440) return;
  int o = idx / 1440, rem = idx - o*1440;
  int tap = rem / 160, c = rem - tap*160;
  float vv = (c < 136) ? w[(size_t)(o*136 + c)*9 + tap] : 0.f;
  wzb[idx] = f2b(vv);
}

// ============ K11: conv_z via MFMA bf16 (im2col GEMM, 9 taps x K=160) ========
// block: 64 pixels (one row segment) x 128 out-ch; 4 waves, wave w -> o in [32w,32w+32)
__global__ __launch_bounds__(256,1) void conv_z_mfma(
    const float* __restrict__ z, const float* __restrict__ alpha,
    const float* __restrict__ st, const unsigned short* __restrict__ wzb,
    const float* __restrict__ bias, float* __restrict__ out){
  __shared__ __align__(16) unsigned short xs[3*66*192];   // 76032 B, XOR-swizzled
  __shared__ __align__(16) unsigned short wsm[128*192];   // 49152 B, XOR-swizzled
  __shared__ float ms[136], isd[136];
  int t = threadIdx.x;
  int p = blockIdx.x;
  int i = p >> 2, j0 = (p & 3) * 64;
  if (t < 136){ ms[t] = st[t]; isd[t] = st[136 + t]; }
  __syncthreads();
  // stage xs: 3 rows x 66 cols x 40 channel-quads (136 real ch + zero pad to 160)
  for (int idx = t; idx < 7920; idx += 256){
    int r = idx / (66*40);
    int rem = idx - r*(66*40);
    int col = rem / 40;
    int cq = rem - col*40;
    int row = i - 1 + r;
    int gj = j0 - 1 + col;
    float4 vv = {0.f,0.f,0.f,0.f};
    if (row >= 0 && row < 256 && gj >= 0 && gj < 256){
      size_t pix = (size_t)row*256 + gj;
      if (cq < 32){
        float4 raw = *(const float4*)(z + pix*128 + cq*4);
        int c = cq*4;
        vv.x = (raw.x - ms[c  ])*isd[c  ];
        vv.y = (raw.y - ms[c+1])*isd[c+1];
        vv.z = (raw.z - ms[c+2])*isd[c+2];
        vv.w = (raw.w - ms[c+3])*isd[c+3];
      } else if (cq < 34){
        float4 raw = *(const float4*)(alpha + pix*8 + (cq-32)*4);
        int c = cq*4;
        vv.x = (raw.x - ms[c  ])*isd[c  ];
        vv.y = (raw.y - ms[c+1])*isd[c+1];
        vv.z = (raw.z - ms[c+2])*isd[c+2];
        vv.w = (raw.w - ms[c+3])*isd[c+3];
      }
    }
    ushort4 wb;
    wb.x = f2b(vv.x); wb.y = f2b(vv.y); wb.z = f2b(vv.z); wb.w = f2b(vv.w);
    int elemoff = (r*66 + col)*192 + (((cq>>1)*8) ^ ((col&7)*8)) + (cq&1)*4;
    *(ushort4*)(xs + elemoff) = wb;
  }
  // stage wsm tap 0
  for (int idx = t; idx < 2560; idx += 256){
    int o = idx / 20, cb = idx - o*20;
    uint4 wv = *(const uint4*)(wzb + (size_t)o*1440 + cb*8);
    *(uint4*)(wsm + o*192 + ((cb*8) ^ ((o&7)*8))) = wv;
  }
  __syncthreads();

  int lane = t & 63;
  int wid = t >> 6;
  int wo = wid * 32;
  int li = lane & 15, lg = lane >> 4;
  f32x4 acc[4][2];
  #pragma unroll
  for (int a = 0; a < 4; a++)
    #pragma unroll
    for (int b = 0; b < 2; b++) acc[a][b] = (f32x4){0.f,0.f,0.f,0.f};
  uint4 wpf[10];
  int ob0 = wo + li, ob1 = wo + 16 + li;
  int bo0 = ob0*192, bs0 = (ob0&7)*8;
  int bo1 = ob1*192, bs1 = (ob1&7)*8;
  for (int tap = 0; tap < 9; ++tap){
    int kh = tap/3, kw = tap - kh*3;
    if (tap < 8){
      #pragma unroll
      for (int it = 0; it < 10; ++it){
        int idx = t + it*256;
        int o = idx / 20, cb = idx - o*20;
        wpf[it] = *(const uint4*)(wzb + (size_t)o*1440 + (tap+1)*160 + cb*8);
      }
    }
    #pragma unroll
    for (int c0i = 0; c0i < 5; ++c0i){
      int ce = c0i*32 + lg*8;
      bf16x8 b0 = *(const bf16x8*)(wsm + bo0 + (ce ^ bs0));
      bf16x8 b1 = *(const bf16x8*)(wsm + bo1 + (ce ^ bs1));
      #pragma unroll
      for (int mf = 0; mf < 4; ++mf){
        int col = mf*16 + li + kw;
        bf16x8 a = *(const bf16x8*)(xs + (kh*66 + col)*192 + (ce ^ ((col&7)*8)));
        acc[mf][0] = __builtin_amdgcn_mfma_f32_16x16x32_bf16(a, b0, acc[mf][0], 0, 0, 0);
        acc[mf][1] = __builtin_amdgcn_mfma_f32_16x16x32_bf16(a, b1, acc[mf][1], 0, 0, 0);
      }
    }
    __syncthreads();
    if (tap < 8){
      #pragma unroll
      for (int it = 0; it < 10; ++it){
        int idx = t + it*256;
        int o = idx / 20, cb = idx - o*20;
        *(uint4*)(wsm + o*192 + ((cb*8) ^ ((o&7)*8))) = wpf[it];
      }
      __syncthreads();
    }
  }
  float bb0 = bias[wo + li], bb1 = bias[wo + 16 + li];
  #pragma unroll
  for (int mf = 0; mf < 4; ++mf){
    #pragma unroll
    for (int ri = 0; ri < 4; ++ri){
      int px = mf*16 + lg*4 + ri;
      size_t obase = ((size_t)(i*256 + j0 + px))*128;
      float v0 = acc[mf][0][ri] + bb0;
      float v1 = acc[mf][1][ri] + bb1;
      out[obase + wo + li]      = (v0 >= 0.f) ? v0 : 0.01f*v0;
      out[obase + wo + 16 + li] = (v1 >= 0.f) ? v1 : 0.01f*v1;
    }
  }
}

extern "C" void kernel_launch(void* const* d_in, const int* in_sizes, int n_in,
                              void* d_out, int out_size, void* d_ws, size_t ws_size,
                              hipStream_t stream){
  const float* x        = (const float*)d_in[0];
  const float* z        = (const float*)d_in[1];
  const float* plddt    = (const float*)d_in[2];
  const float* Wq       = (const float*)d_in[3];
  const float* Wk       = (const float*)d_in[4];
  const float* Wv       = (const float*)d_in[5];
  const float* Wp2a     = (const float*)d_in[6];
  const float* conv_a_w = (const float*)d_in[7];
  const float* conv_a_b = (const float*)d_in[8];
  const float* conv_p_w = (const float*)d_in[9];
  const float* conv_p_b = (const float*)d_in[10];
  const float* ln1_g    = (const float*)d_in[11];
  const float* ln1_b    = (const float*)d_in[12];
  const float* lin1_w   = (const float*)d_in[13];
  const float* lin1_b   = (const float*)d_in[14];
  const float* ln2_g    = (const float*)d_in[15];
  const float* ln2_b    = (const float*)d_in[16];
  const float* lin2_w   = (const float*)d_in[17];
  const float* lin2_b   = (const float*)d_in[18];
  const float* lnf_g    = (const float*)d_in[19];
  const float* lnf_b    = (const float*)d_in[20];
  const float* conv_z_w = (const float*)d_in[21];
  const float* conv_z_b = (const float*)d_in[22];

  float* ws    = (float*)d_ws;
  float* q     = ws + OFF_Q;
  float* k     = ws + OFF_K;
  float* v     = ws + OFF_V;
  float* cat16 = ws + OFF_CAT16;
  float* a1    = ws + OFF_A1;
  float* alpha = ws + OFF_ALPHA;
  float* agg   = ws + OFF_AGG;
  float* st16  = ws + OFF_ST16;
  float* st9   = ws + OFF_ST9;
  float* st136 = ws + OFF_ST136;
  unsigned short* wzb = (unsigned short*)(ws + OFF_WZB);
  float* y     = ws + OFF_Y;

  float* xout = (float*)d_out;
  float* zout = (float*)d_out + 65536;

  qkv_kernel<<<dim3(32,3), 256, 0, stream>>>(x, Wq, Wk, Wv, q, k, v);
  cat16_kernel<<<2048, 256, 0, stream>>>(z, q, k, Wp2a, cat16);
  stats_kernel<<<16, 256, 0, stream>>>(cat16, 16, (const float*)nullptr, 0, st16);
  conv_small_kernel<16,8><<<256, 256, 0, stream>>>(cat16, 16, (const float*)nullptr, 0,
                                                   st16, conv_a_w, conv_a_b, a1);
  stats_kernel<<<9, 256, 0, stream>>>(a1, 8, plddt, 1, st9);
  conv_small_kernel<9,8><<<256, 256, 0, stream>>>(a1, 8, plddt, 1,
                                                  st9, conv_p_w, conv_p_b, alpha);
  agg_kernel<<<256, 256, 0, stream>>>(alpha, z, v, agg);
  outA_kernel<<<128, 256, 0, stream>>>(agg, ln1_g, ln1_b, lin1_w, lin1_b, y);
  outB_kernel<<<32, 256, 0, stream>>>(y, x, ln2_g, ln2_b, lin2_w, lin2_b,
                                      lnf_g, lnf_b, xout);
  stats_kernel<<<136, 256, 0, stream>>>(z, 128, alpha, 8, st136);
  wz_prep<<<720, 256, 0, stream>>>(conv_z_w, wzb);
  conv_z_mfma<<<1024, 256, 0, stream>>>(z, alpha, st136, wzb, conv_z_b, zout);
}

// Round 5
// 366.217 us; speedup vs baseline: 1.9985x; 1.4499x over previous
//
#include <hip/hip_runtime.h>
#include <math.h>

#define LLEN 256
#define NDIM 256
#define NHEAD 8
#define HDIM 32
#define NPIX (LLEN*LLEN)

typedef __bf16 bf16x8 __attribute__((ext_vector_type(8)));
typedef float f32x4 __attribute__((ext_vector_type(4)));

// ---- workspace layout (float offsets) ----
constexpr size_t OFF_Q     = 0;          // 65536
constexpr size_t OFF_K     = 65536;
constexpr size_t OFF_V     = 131072;
constexpr size_t OFF_CAT16 = 196608;     // 1048576
constexpr size_t OFF_A1    = 1245184;    // 524288
constexpr size_t OFF_ALPHA = 1769472;    // 524288
constexpr size_t OFF_AGG   = 2293760;    // 327680
constexpr size_t OFF_Y     = 2621440;    // 131072
constexpr size_t OFF_ST16  = 2752512;    // 32
constexpr size_t OFF_ST9   = 2752544;    // 32
constexpr size_t OFF_ST136 = 2752576;    // 288
constexpr size_t OFF_PART  = 2752864;    // 136*1024
constexpr size_t OFF_PART2 = 2892128;    // 136*1024
constexpr size_t OFF_WZB2  = 3031392;    // 184320 shorts = 92160 floats
// total ~3,123,552 floats = 12.5 MB

__device__ inline unsigned short f2b(float x){
  union { float f; unsigned u; } a; a.f = x;
  unsigned r = a.u + 0x7fffu + ((a.u >> 16) & 1u);
  return (unsigned short)(r >> 16);
}

// ============ K1: q,k,v = x @ W^T ============
__global__ __launch_bounds__(256) void qkv_kernel(
    const float* __restrict__ x, const float* __restrict__ Wq,
    const float* __restrict__ Wk, const float* __restrict__ Wv,
    float* __restrict__ q, float* __restrict__ k, float* __restrict__ v){
  __shared__ __align__(16) float xs[8][256];
  int t = threadIdx.x;
  int i0 = blockIdx.x * 8;
  int m = blockIdx.y;
  const float* W = (m==0)?Wq:((m==1)?Wk:Wv);
  float* out = (m==0)?q:((m==1)?k:v);
  for (int idx = t; idx < 2048; idx += 256)
    xs[idx>>8][idx&255] = x[(size_t)i0*256 + idx];
  __syncthreads();
  float acc[8];
  #pragma unroll
  for (int r = 0; r < 8; r++) acc[r] = 0.f;
  const float4* wr = (const float4*)(W + (size_t)t*256);
  for (int kk = 0; kk < 64; ++kk){
    float4 w4 = wr[kk];
    #pragma unroll
    for (int r = 0; r < 8; r++){
      float4 xv = ((const float4*)xs[r])[kk];
      acc[r] += w4.x*xv.x + w4.y*xv.y + w4.z*xv.z + w4.w*xv.w;
    }
  }
  #pragma unroll
  for (int r = 0; r < 8; r++) out[(size_t)(i0+r)*256 + t] = acc[r];
}

// ============ K2: cat16 = [a_pair(8) | a_node(8)] ============
__global__ __launch_bounds__(256) void cat16_kernel(
    const float* __restrict__ z, const float* __restrict__ qb,
    const float* __restrict__ kb, const float* __restrict__ Wp2a,
    float* __restrict__ cat16){
  __shared__ float zs[32*128];
  __shared__ float wsm[8*128];
  __shared__ float qs[256];
  __shared__ float ks[32*256];
  int t = threadIdx.x;
  int pix0 = blockIdx.x * 32;
  int i = pix0 >> 8;
  int j0 = pix0 & 255;
  for (int idx = t; idx < 8*128; idx += 256) wsm[idx] = Wp2a[idx];
  qs[t] = qb[i*NDIM + t];
  for (int idx = t; idx < 32*128; idx += 256) zs[idx] = z[(size_t)pix0*128 + idx];
  for (int idx = t; idx < 32*256; idx += 256) ks[idx] = kb[(size_t)j0*NDIM + idx];
  __syncthreads();
  int p8 = t >> 3, h = t & 7;
  const float* zp = zs + p8*128;
  const float* wp = wsm + h*128;
  float ap = 0.f;
  #pragma unroll 8
  for (int p = 0; p < 128; p++) ap += zp[p]*wp[p];
  const float* qh = qs + h*32;
  const float* kh_ = ks + p8*256 + h*32;
  float an = 0.f;
  #pragma unroll
  for (int d = 0; d < HDIM; d++) an += qh[d]*kh_[d];
  an *= 0.17677669529663689f;
  int pix = pix0 + p8;
  cat16[(size_t)pix*16 + h] = ap;
  cat16[(size_t)pix*16 + 8 + h] = an;
}

// ============ coalesced two-stage instance-norm stats ============
// stage A for z (128ch, NHWC stride 128): 1024 blocks x 64 px
__global__ __launch_bounds__(256) void statsA_z_kernel(
    const float* __restrict__ z, float* __restrict__ part, float* __restrict__ part2){
  __shared__ float4 sm[256], sq[256];
  int t = threadIdx.x, b = blockIdx.x;
  int c4 = t & 31, po = t >> 5;
  float4 s = {0,0,0,0}, q = {0,0,0,0};
  for (int g = 0; g < 8; ++g){
    int px = b*64 + po + g*8;
    float4 v = *(const float4*)(z + (size_t)px*128 + c4*4);
    s.x += v.x; s.y += v.y; s.z += v.z; s.w += v.w;
    q.x += v.x*v.x; q.y += v.y*v.y; q.z += v.z*v.z; q.w += v.w*v.w;
  }
  sm[t] = s; sq[t] = q;
  __syncthreads();
  if (t < 32){
    float4 S = sm[t], Q = sq[t];
    for (int p2 = 1; p2 < 8; ++p2){
      float4 a = sm[p2*32 + t], c = sq[p2*32 + t];
      S.x += a.x; S.y += a.y; S.z += a.z; S.w += a.w;
      Q.x += c.x; Q.y += c.y; Q.z += c.z; Q.w += c.w;
    }
    part [(size_t)(t*4+0)*1024 + b] = S.x; part [(size_t)(t*4+1)*1024 + b] = S.y;
    part [(size_t)(t*4+2)*1024 + b] = S.z; part [(size_t)(t*4+3)*1024 + b] = S.w;
    part2[(size_t)(t*4+0)*1024 + b] = Q.x; part2[(size_t)(t*4+1)*1024 + b] = Q.y;
    part2[(size_t)(t*4+2)*1024 + b] = Q.z; part2[(size_t)(t*4+3)*1024 + b] = Q.w;
  }
}

// stage A for 16-ch tensor (cat16): 256 blocks x 256 px
__global__ __launch_bounds__(256) void statsA_16_kernel(
    const float* __restrict__ src, float* __restrict__ part, float* __restrict__ part2){
  __shared__ float4 sm[256], sq[256];
  int t = threadIdx.x, b = blockIdx.x;
  int c4 = t & 3, po = t >> 2;
  float4 s = {0,0,0,0}, q = {0,0,0,0};
  for (int g = 0; g < 4; ++g){
    int px = b*256 + po + g*64;
    float4 v = *(const float4*)(src + (size_t)px*16 + c4*4);
    s.x += v.x; s.y += v.y; s.z += v.z; s.w += v.w;
    q.x += v.x*v.x; q.y += v.y*v.y; q.z += v.z*v.z; q.w += v.w*v.w;
  }
  sm[t] = s; sq[t] = q;
  __syncthreads();
  if (t < 4){
    float4 S = sm[t], Q = sq[t];
    for (int p2 = 1; p2 < 64; ++p2){
      float4 a = sm[p2*4 + t], c = sq[p2*4 + t];
      S.x += a.x; S.y += a.y; S.z += a.z; S.w += a.w;
      Q.x += c.x; Q.y += c.y; Q.z += c.z; Q.w += c.w;
    }
    part [(size_t)(t*4+0)*1024 + b] = S.x; part [(size_t)(t*4+1)*1024 + b] = S.y;
    part [(size_t)(t*4+2)*1024 + b] = S.z; part [(size_t)(t*4+3)*1024 + b] = S.w;
    part2[(size_t)(t*4+0)*1024 + b] = Q.x; part2[(size_t)(t*4+1)*1024 + b] = Q.y;
    part2[(size_t)(t*4+2)*1024 + b] = Q.z; part2[(size_t)(t*4+3)*1024 + b] = Q.w;
  }
}

// stage A for 8-ch tensor (a1 / alpha): 256 blocks x 256 px
__global__ __launch_bounds__(256) void statsA_s8_kernel(
    const float* __restrict__ src, float* __restrict__ part, float* __restrict__ part2,
    int coff){
  __shared__ float sm[256], sq[256];
  int t = threadIdx.x, b = blockIdx.x;
  int ch = t & 7, po = t >> 3;
  float s = 0.f, q = 0.f;
  for (int g = 0; g < 8; ++g){
    int px = b*256 + po + g*32;
    float v = src[(size_t)px*8 + ch];
    s += v; q += v*v;
  }
  sm[t] = s; sq[t] = q;
  __syncthreads();
  if (t < 8){
    float S = 0.f, Q = 0.f;
    for (int p2 = 0; p2 < 32; ++p2){ S += sm[p2*8 + t]; Q += sq[p2*8 + t]; }
    part [(size_t)(coff+t)*1024 + b] = S;
    part2[(size_t)(coff+t)*1024 + b] = Q;
  }
}

__device__ inline void block_reduce2(float& s, float& s2, float* red){
  int t = threadIdx.x;
  int lane = t & 63, wv = t >> 6;
  #pragma unroll
  for (int o = 32; o > 0; o >>= 1){ s += __shfl_down(s, o); s2 += __shfl_down(s2, o); }
  __syncthreads();
  if (lane == 0){ red[wv] = s; red[4+wv] = s2; }
  __syncthreads();
  s  = red[0]+red[1]+red[2]+red[3];
  s2 = red[4]+red[5]+red[6]+red[7];
}

// stage A for 1-ch tensor (plddt): 256 blocks x 256 px
__global__ __launch_bounds__(256) void statsA_s1_kernel(
    const float* __restrict__ src, float* __restrict__ part, float* __restrict__ part2,
    int coff){
  __shared__ float red[8];
  int t = threadIdx.x, b = blockIdx.x;
  float v = src[(size_t)b*256 + t];
  float s = v, q = v*v;
  block_reduce2(s, q, red);
  if (t == 0){ part[(size_t)coff*1024 + b] = s; part2[(size_t)coff*1024 + b] = q; }
}

// stage B: reduce partials -> (mean, inv-std)
__global__ __launch_bounds__(256) void statsB_kernel(
    const float* __restrict__ part, const float* __restrict__ part2,
    float* __restrict__ st, int C, int csplit, int nb_main, int nb_tail){
  __shared__ float red[8];
  int c = blockIdx.x, t = threadIdx.x;
  int nb = (c < csplit) ? nb_main : nb_tail;
  float s = 0.f, q = 0.f;
  for (int i = t; i < nb; i += 256){ s += part[(size_t)c*1024 + i]; q += part2[(size_t)c*1024 + i]; }
  block_reduce2(s, q, red);
  if (t == 0){
    float m = s * (1.f/NPIX);
    float var = q * (1.f/NPIX) - m*m;
    st[c] = m;
    st[C + c] = rsqrtf(var + 1e-5f);
  }
}

// ============ small conv 3x3 (CIN->COUT) fused inorm + lrelu ============
template<int CIN, int COUT>
__global__ __launch_bounds__(256) void conv_small_kernel(
    const float* __restrict__ A, int Ca, const float* __restrict__ B, int Cb,
    const float* __restrict__ st, const float* __restrict__ w,
    const float* __restrict__ bias, float* __restrict__ out){
  __shared__ float xn[3][256][CIN];
  __shared__ float wsm[COUT*CIN*9];
  __shared__ float ms[CIN], isd[CIN], bs[COUT];
  int i = blockIdx.x, t = threadIdx.x;
  if (t < CIN){ ms[t] = st[t]; isd[t] = st[CIN + t]; }
  if (t < COUT) bs[t] = bias[t];
  for (int idx = t; idx < COUT*CIN*9; idx += 256) wsm[idx] = w[idx];
  __syncthreads();
  for (int r = 0; r < 3; r++){
    int row = i - 1 + r;
    for (int idx = t; idx < 256*CIN; idx += 256){
      int col = idx / CIN, c = idx - col*CIN;
      float vv = 0.f;
      if (row >= 0 && row < 256){
        size_t pix = (size_t)row*256 + col;
        float raw = (c < Ca) ? A[pix*Ca + c] : B[pix*Cb + (c - Ca)];
        vv = (raw - ms[c]) * isd[c];
      }
      xn[r][col][c] = vv;
    }
  }
  __syncthreads();
  int j = t;
  float acc[COUT];
  #pragma unroll
  for (int o = 0; o < COUT; o++) acc[o] = bs[o];
  #pragma unroll
  for (int kh = 0; kh < 3; kh++){
    #pragma unroll
    for (int kw = 0; kw < 3; kw++){
      int jj = j + kw - 1;
      if (jj < 0 || jj > 255) continue;
      float vreg[CIN];
      #pragma unroll
      for (int c = 0; c < CIN; c++) vreg[c] = xn[kh][jj][c];
      #pragma unroll
      for (int o = 0; o < COUT; o++){
        float a = 0.f;
        #pragma unroll
        for (int c = 0; c < CIN; c++) a += vreg[c]*wsm[((o*CIN + c)*3 + kh)*3 + kw];
        acc[o] += a;
      }
    }
  }
  #pragma unroll
  for (int o = 0; o < COUT; o++){
    float vv = acc[o];
    out[((size_t)(i*256 + j))*COUT + o] = (vv >= 0.f) ? vv : 0.01f*vv;
  }
}

// ============ aggregation ============
__global__ __launch_bounds__(256) void agg_kernel(
    const float* __restrict__ alpha, const float* __restrict__ z,
    const float* __restrict__ v, float* __restrict__ agg){
  __shared__ float as[256*8];
  int i = blockIdx.x, t = threadIdx.x;
  for (int idx = t; idx < 2048; idx += 256) as[idx] = alpha[(size_t)i*2048 + idx];
  __syncthreads();
  int p = t & 127, hh = t >> 7;
  const float* zrow = z + (size_t)i*(256*128);
  float a0=0.f, a1=0.f, a2=0.f, a3=0.f;
  for (int j = 0; j < 256; j++){
    float zv = zrow[j*128 + p];
    const float* ar = as + j*8 + hh*4;
    a0 += ar[0]*zv; a1 += ar[1]*zv; a2 += ar[2]*zv; a3 += ar[3]*zv;
  }
  size_t ob = (size_t)i*1280;
  agg[ob + (hh*4+0)*128 + p] = a0;
  agg[ob + (hh*4+1)*128 + p] = a1;
  agg[ob + (hh*4+2)*128 + p] = a2;
  agg[ob + (hh*4+3)*128 + p] = a3;
  int h = t >> 5;
  float an = 0.f;
  for (int j = 0; j < 256; j++) an += as[j*8 + h]*v[(size_t)j*256 + t];
  agg[ob + 1024 + t] = an;
}

// ============ out_transform ============
__global__ __launch_bounds__(256) void outA_kernel(
    const float* __restrict__ agg,
    const float* __restrict__ ln1_g, const float* __restrict__ ln1_b,
    const float* __restrict__ lin1_w, const float* __restrict__ lin1_b,
    float* __restrict__ y){
  __shared__ __align__(16) float h1[8][1280];
  __shared__ float red[8];
  int t = threadIdx.x;
  int rb = blockIdx.x >> 2, ob = blockIdx.x & 3;
  for (int r = 0; r < 8; ++r){
    int i = rb*8 + r;
    float v[5], s = 0.f, s2 = 0.f;
    #pragma unroll
    for (int qq = 0; qq < 5; ++qq){
      v[qq] = agg[(size_t)i*1280 + qq*256 + t];
      s += v[qq]; s2 += v[qq]*v[qq];
    }
    block_reduce2(s, s2, red);
    float m = s*(1.f/1280.f), istd = rsqrtf(s2*(1.f/1280.f) - m*m + 1e-5f);
    #pragma unroll
    for (int qq = 0; qq < 5; ++qq){
      int kk = qq*256 + t;
      h1[r][kk] = (v[qq] - m)*istd*ln1_g[kk] + ln1_b[kk];
    }
  }
  __syncthreads();
  int o = ob*128 + (t & 127);
  int half = t >> 7;
  float a0=0.f, a1=0.f, a2=0.f, a3=0.f;
  const float4* wr = (const float4*)(lin1_w + (size_t)o*1280);
  const float4* r0 = (const float4*)h1[half*4+0];
  const float4* r1 = (const float4*)h1[half*4+1];
  const float4* r2 = (const float4*)h1[half*4+2];
  const float4* r3 = (const float4*)h1[half*4+3];
  for (int kk = 0; kk < 320; ++kk){
    float4 w4 = wr[kk];
    float4 x0 = r0[kk]; a0 += w4.x*x0.x + w4.y*x0.y + w4.z*x0.z + w4.w*x0.w;
    float4 x1 = r1[kk]; a1 += w4.x*x1.x + w4.y*x1.y + w4.z*x1.z + w4.w*x1.w;
    float4 x2 = r2[kk]; a2 += w4.x*x2.x + w4.y*x2.y + w4.z*x2.z + w4.w*x2.w;
    float4 x3 = r3[kk]; a3 += w4.x*x3.x + w4.y*x3.y + w4.z*x3.z + w4.w*x3.w;
  }
  int i0 = rb*8 + half*4;
  float bb = lin1_b[o];
  y[(size_t)(i0+0)*512 + o] = a0 + bb;
  y[(size_t)(i0+1)*512 + o] = a1 + bb;
  y[(size_t)(i0+2)*512 + o] = a2 + bb;
  y[(size_t)(i0+3)*512 + o] = a3 + bb;
}

__global__ __launch_bounds__(256) void outB_kernel(
    const float* __restrict__ y, const float* __restrict__ x,
    const float* __restrict__ ln2_g, const float* __restrict__ ln2_b,
    const float* __restrict__ lin2_w, const float* __restrict__ lin2_b,
    const float* __restrict__ lnf_g, const float* __restrict__ lnf_b,
    float* __restrict__ xout){
  __shared__ __align__(16) float h2[8][512];
  __shared__ float red[8];
  int t = threadIdx.x;
  int rb = blockIdx.x;
  for (int r = 0; r < 8; ++r){
    int i = rb*8 + r;
    float y0 = y[(size_t)i*512 + t], y1 = y[(size_t)i*512 + 256 + t];
    float s = y0 + y1, s2 = y0*y0 + y1*y1;
    block_reduce2(s, s2, red);
    float m = s*(1.f/512.f), istd = rsqrtf(s2*(1.f/512.f) - m*m + 1e-5f);
    float z0 = (y0 - m)*istd*ln2_g[t] + ln2_b[t];
    float z1 = (y1 - m)*istd*ln2_g[t+256] + ln2_b[t+256];
    h2[r][t]     = (z0 >= 0.f) ? z0 : 0.01f*z0;
    h2[r][t+256] = (z1 >= 0.f) ? z1 : 0.01f*z1;
  }
  __syncthreads();
  float acc[8];
  #pragma unroll
  for (int r = 0; r < 8; ++r) acc[r] = 0.f;
  const float4* wr = (const float4*)(lin2_w + (size_t)t*512);
  for (int kk = 0; kk < 128; ++kk){
    float4 w4 = wr[kk];
    #pragma unroll
    for (int r = 0; r < 8; ++r){
      float4 h = ((const float4*)h2[r])[kk];
      acc[r] += w4.x*h.x + w4.y*h.y + w4.z*h.z + w4.w*h.w;
    }
  }
  float bb = lin2_b[t];
  for (int r = 0; r < 8; ++r){
    int i = rb*8 + r;
    float xr = x[(size_t)i*256 + t] + acc[r] + bb;
    float s = xr, s2 = xr*xr;
    block_reduce2(s, s2, red);
    float m = s*(1.f/256.f), istd = rsqrtf(s2*(1.f/256.f) - m*m + 1e-5f);
    xout[(size_t)i*256 + t] = (xr - m)*istd*lnf_g[t] + lnf_b[t];
  }
}

// ============ conv_z weight pack: B-fragments [ocb][tap][k][lane][8] ============
__global__ __launch_bounds__(256) void wz_prep2(const float* __restrict__ w,
                                                unsigned short* __restrict__ wzb2){
  int idx = blockIdx.x*256 + threadIdx.x;
  if (idx >= 23040) return;
  int lane = idx & 63;
  int f = idx >> 6;
  int k = f % 5; int ft = f / 5; int tap = ft % 9; int ocb = ft / 9;
  int oc = ocb*16 + (lane & 15);
  int chb = k*32 + (lane >> 4)*8;
  unsigned short u[8];
  #pragma unroll
  for (int j = 0; j < 8; ++j){
    int ch = chb + j;
    float vv = (ch < 136) ? w[(size_t)oc*1224 + ch*9 + tap] : 0.f;
    u[j] = f2b(vv);
  }
  uint4 pk;
  pk.x = (unsigned)u[0] | ((unsigned)u[1]<<16);
  pk.y = (unsigned)u[2] | ((unsigned)u[3]<<16);
  pk.z = (unsigned)u[4] | ((unsigned)u[5]<<16);
  pk.w = (unsigned)u[6] | ((unsigned)u[7]<<16);
  *(uint4*)(wzb2 + (size_t)idx*8) = pk;
}

// ============ conv_z rolling-row MFMA kernel ============
// grid 512: stripe = bid&7 (32 output cols), rowgroup = bid>>3 (4 output rows)
// 256 threads = 4 waves; wave w owns oc [w*32, w*32+32)
struct StageRegs { float4 a[3], b[3]; };

__device__ inline void stage_load(const float* __restrict__ z,
                                  const float* __restrict__ alpha,
                                  int ir, int c0, int t, StageRegs& R){
  #pragma unroll
  for (int it = 0; it < 3; ++it){
    int cidx = t + it*256;
    float4 r0 = {0.f,0.f,0.f,0.f}, r1 = {0.f,0.f,0.f,0.f};
    if (cidx < 578){
      int col = cidx / 17, cq = cidx - col*17;
      int gcol = c0 + col - 1;
      if (ir >= 0 && ir < 256 && gcol >= 0 && gcol < 256){
        const float* src = (cq < 16) ? (z + ((size_t)ir*256 + gcol)*128 + cq*8)
                                     : (alpha + ((size_t)ir*256 + gcol)*8);
        r0 = *(const float4*)src;
        r1 = *(const float4*)(src + 4);
      }
    }
    R.a[it] = r0; R.b[it] = r1;
  }
}

__device__ inline void stage_write(unsigned short* xs, const float* ms, const float* isd,
                                   int slot, int t, int ir, int c0, const StageRegs& R){
  #pragma unroll
  for (int it = 0; it < 3; ++it){
    int cidx = t + it*256;
    if (cidx >= 578) continue;
    int col = cidx / 17, cq = cidx - col*17;
    int gcol = c0 + col - 1;
    bool valid = (ir >= 0 && ir < 256 && gcol >= 0 && gcol < 256);
    uint4 pk = {0u,0u,0u,0u};
    if (valid){
      int ch = cq*8;
      float4 r0 = R.a[it], r1 = R.b[it];
      unsigned short u0 = f2b((r0.x - ms[ch+0])*isd[ch+0]);
      unsigned short u1 = f2b((r0.y - ms[ch+1])*isd[ch+1]);
      unsigned short u2 = f2b((r0.z - ms[ch+2])*isd[ch+2]);
      unsigned short u3 = f2b((r0.w - ms[ch+3])*isd[ch+3]);
      unsigned short u4 = f2b((r1.x - ms[ch+4])*isd[ch+4]);
      unsigned short u5 = f2b((r1.y - ms[ch+5])*isd[ch+5]);
      unsigned short u6 = f2b((r1.z - ms[ch+6])*isd[ch+6]);
      unsigned short u7 = f2b((r1.w - ms[ch+7])*isd[ch+7]);
      pk.x = (unsigned)u0 | ((unsigned)u1<<16);
      pk.y = (unsigned)u2 | ((unsigned)u3<<16);
      pk.z = (unsigned)u4 | ((unsigned)u5<<16);
      pk.w = (unsigned)u6 | ((unsigned)u7<<16);
    }
    *(uint4*)(xs + ((size_t)slot*578 + cidx)*8) = pk;
  }
}

#define LOADB(B, TAP) { \
  _Pragma("unroll") \
  for (int k_ = 0; k_ < 5; ++k_){ \
    _Pragma("unroll") \
    for (int o_ = 0; o_ < 2; ++o_){ \
      B[k_][o_] = *(const bf16x8*)(wzb2 + (size_t)((((wocb+o_)*9 + (TAP))*5 + k_)*64 + lane)*8); \
    } } }

#define CTAP(TAP, B) { \
  const int kh_ = (TAP)/3, kw_ = (TAP)%3; \
  const unsigned short* sb_ = xs + (size_t)((r + kh_)&3)*578*8; \
  _Pragma("unroll") \
  for (int k_ = 0; k_ < 5; ++k_){ \
    int cq_ = (k_ < 4) ? (k_*4 + lg) : 16; \
    bf16x8 a0_ = *(const bf16x8*)(sb_ + ((li+kw_)*17 + cq_)*8); \
    bf16x8 a1_ = *(const bf16x8*)(sb_ + ((li+kw_+16)*17 + cq_)*8); \
    acc00 = __builtin_amdgcn_mfma_f32_16x16x32_bf16(a0_, B[k_][0], acc00, 0,0,0); \
    acc01 = __builtin_amdgcn_mfma_f32_16x16x32_bf16(a0_, B[k_][1], acc01, 0,0,0); \
    acc10 = __builtin_amdgcn_mfma_f32_16x16x32_bf16(a1_, B[k_][0], acc10, 0,0,0); \
    acc11 = __builtin_amdgcn_mfma_f32_16x16x32_bf16(a1_, B[k_][1], acc11, 0,0,0); \
  } }

__global__ __launch_bounds__(256) void conv_z2_kernel(
    const float* __restrict__ z, const float* __restrict__ alpha,
    const float* __restrict__ st, const unsigned short* __restrict__ wzb2,
    const float* __restrict__ bias, float* __restrict__ out){
  __shared__ __align__(16) unsigned short xs[4*578*8];   // 36,992 B
  __shared__ float msld[136], isdld[136];
  __shared__ __align__(16) float out32[32*132];          // 16,896 B
  int t = threadIdx.x;
  int stripe = blockIdx.x & 7, rg = blockIdx.x >> 3;
  int i0 = rg*4, c0 = stripe*32;
  int lane = t & 63, w = t >> 6;
  int li = lane & 15, lg = lane >> 4;
  int wocb = w*2;
  if (t < 136){ msld[t] = st[t]; isdld[t] = st[136 + t]; }
  __syncthreads();
  // prologue: stage input rows i0-1, i0, i0+1 into slots 0,1,2
  for (int kk = 0; kk < 3; ++kk){
    StageRegs R;
    stage_load(z, alpha, i0-1+kk, c0, t, R);
    stage_write(xs, msld, isdld, kk, t, i0-1+kk, c0, R);
  }
  float4 b4 = *(const float4*)(bias + (t & 31)*4);
  __syncthreads();

  for (int r = 0; r < 4; ++r){
    int i = i0 + r;
    StageRegs R;
    if (r < 3) stage_load(z, alpha, i+2, c0, t, R);   // T14: issue early

    f32x4 acc00 = {0.f,0.f,0.f,0.f}, acc01 = acc00, acc10 = acc00, acc11 = acc00;
    bf16x8 b0[5][2], b1[5][2];
    LOADB(b0, 0);
    LOADB(b1, 1); CTAP(0, b0);
    LOADB(b0, 2); CTAP(1, b1);
    LOADB(b1, 3); CTAP(2, b0);
    LOADB(b0, 4); CTAP(3, b1);
    LOADB(b1, 5); CTAP(4, b0);
    LOADB(b0, 6); CTAP(5, b1);
    LOADB(b1, 7); CTAP(6, b0);
    LOADB(b0, 8); CTAP(7, b1);
    CTAP(8, b0);

    // acc -> out32 (padded 132 to avoid bank conflicts)
    #pragma unroll
    for (int ri = 0; ri < 4; ++ri){
      out32[(lg*4 + ri)*132      + (wocb+0)*16 + li] = acc00[ri];
      out32[(lg*4 + ri)*132      + (wocb+1)*16 + li] = acc01[ri];
      out32[(16 + lg*4 + ri)*132 + (wocb+0)*16 + li] = acc10[ri];
      out32[(16 + lg*4 + ri)*132 + (wocb+1)*16 + li] = acc11[ri];
    }
    if (r < 3) stage_write(xs, msld, isdld, (r+3)&3, t, i+2, c0, R);  // T14: write late
    __syncthreads();

    // out32 -> global, coalesced float4
    #pragma unroll
    for (int it = 0; it < 4; ++it){
      int px = (t >> 5) + it*8;
      float4 v = *(const float4*)(out32 + px*132 + (t & 31)*4);
      v.x += b4.x; v.y += b4.y; v.z += b4.z; v.w += b4.w;
      v.x = (v.x >= 0.f) ? v.x : 0.01f*v.x;
      v.y = (v.y >= 0.f) ? v.y : 0.01f*v.y;
      v.z = (v.z >= 0.f) ? v.z : 0.01f*v.z;
      v.w = (v.w >= 0.f) ? v.w : 0.01f*v.w;
      *(float4*)(out + ((size_t)(i*256 + c0 + px))*128 + (t & 31)*4) = v;
    }
    if (r < 3) __syncthreads();
  }
}

extern "C" void kernel_launch(void* const* d_in, const int* in_sizes, int n_in,
                              void* d_out, int out_size, void* d_ws, size_t ws_size,
                              hipStream_t stream){
  const float* x        = (const float*)d_in[0];
  const float* z        = (const float*)d_in[1];
  const float* plddt    = (const float*)d_in[2];
  const float* Wq       = (const float*)d_in[3];
  const float* Wk       = (const float*)d_in[4];
  const float* Wv       = (const float*)d_in[5];
  const float* Wp2a     = (const float*)d_in[6];
  const float* conv_a_w = (const float*)d_in[7];
  const float* conv_a_b = (const float*)d_in[8];
  const float* conv_p_w = (const float*)d_in[9];
  const float* conv_p_b = (const float*)d_in[10];
  const float* ln1_g    = (const float*)d_in[11];
  const float* ln1_b    = (const float*)d_in[12];
  const float* lin1_w   = (const float*)d_in[13];
  const float* lin1_b   = (const float*)d_in[14];
  const float* ln2_g    = (const float*)d_in[15];
  const float* ln2_b    = (const float*)d_in[16];
  const float* lin2_w   = (const float*)d_in[17];
  const float* lin2_b   = (const float*)d_in[18];
  const float* lnf_g    = (const float*)d_in[19];
  const float* lnf_b    = (const float*)d_in[20];
  const float* conv_z_w = (const float*)d_in[21];
  const float* conv_z_b = (const float*)d_in[22];

  float* ws    = (float*)d_ws;
  float* q     = ws + OFF_Q;
  float* k     = ws + OFF_K;
  float* v     = ws + OFF_V;
  float* cat16 = ws + OFF_CAT16;
  float* a1    = ws + OFF_A1;
  float* alpha = ws + OFF_ALPHA;
  float* agg   = ws + OFF_AGG;
  float* y     = ws + OFF_Y;
  float* st16  = ws + OFF_ST16;
  float* st9   = ws + OFF_ST9;
  float* st136 = ws + OFF_ST136;
  float* part  = ws + OFF_PART;
  float* part2 = ws + OFF_PART2;
  unsigned short* wzb2 = (unsigned short*)(ws + OFF_WZB2);

  float* xout = (float*)d_out;
  float* zout = (float*)d_out + 65536;

  qkv_kernel<<<dim3(32,3), 256, 0, stream>>>(x, Wq, Wk, Wv, q, k, v);
  cat16_kernel<<<2048, 256, 0, stream>>>(z, q, k, Wp2a, cat16);
  statsA_16_kernel<<<256, 256, 0, stream>>>(cat16, part, part2);
  statsB_kernel<<<16, 256, 0, stream>>>(part, part2, st16, 16, 16, 256, 256);
  conv_small_kernel<16,8><<<256, 256, 0, stream>>>(cat16, 16, (const float*)nullptr, 0,
                                                   st16, conv_a_w, conv_a_b, a1);
  statsA_s8_kernel<<<256, 256, 0, stream>>>(a1, part, part2, 0);
  statsA_s1_kernel<<<256, 256, 0, stream>>>(plddt, part, part2, 8);
  statsB_kernel<<<9, 256, 0, stream>>>(part, part2, st9, 9, 9, 256, 256);
  conv_small_kernel<9,8><<<256, 256, 0, stream>>>(a1, 8, plddt, 1,
                                                  st9, conv_p_w, conv_p_b, alpha);
  agg_kernel<<<256, 256, 0, stream>>>(alpha, z, v, agg);
  outA_kernel<<<128, 256, 0, stream>>>(agg, ln1_g, ln1_b, lin1_w, lin1_b, y);
  outB_kernel<<<32, 256, 0, stream>>>(y, x, ln2_g, ln2_b, lin2_w, lin2_b,
                                      lnf_g, lnf_b, xout);
  statsA_z_kernel<<<1024, 256, 0, stream>>>(z, part, part2);
  statsA_s8_kernel<<<256, 256, 0, stream>>>(alpha, part, part2, 128);
  statsB_kernel<<<136, 256, 0, stream>>>(part, part2, st136, 136, 128, 1024, 256);
  wz_prep2<<<90, 256, 0, stream>>>(conv_z_w, wzb2);
  conv_z2_kernel<<<512, 256, 0, stream>>>(z, alpha, st136, wzb2, conv_z_b, zout);
}

// Round 6
// 291.953 us; speedup vs baseline: 2.5069x; 1.2544x over previous
//
#include <hip/hip_runtime.h>
#include <math.h>

#define LLEN 256
#define NDIM 256
#define NHEAD 8
#define HDIM 32
#define NPIX (LLEN*LLEN)

typedef __bf16 bf16x8 __attribute__((ext_vector_type(8)));
typedef float f32x4 __attribute__((ext_vector_type(4)));

// ---- workspace layout (float offsets) ----
constexpr size_t OFF_Q     = 0;          // 65536
constexpr size_t OFF_K     = 65536;
constexpr size_t OFF_V     = 131072;
constexpr size_t OFF_CAT16 = 196608;     // 1048576
constexpr size_t OFF_A1    = 1245184;    // 524288
constexpr size_t OFF_ALPHA = 1769472;    // 524288
constexpr size_t OFF_AGG   = 2293760;    // 327680
constexpr size_t OFF_Y     = 2621440;    // 131072
constexpr size_t OFF_ST16  = 2752512;    // 32
constexpr size_t OFF_ST9   = 2752544;    // 32
constexpr size_t OFF_ST136 = 2752576;    // 288
constexpr size_t OFF_PART  = 2752864;    // 136*1024
constexpr size_t OFF_PART2 = 2892128;    // 136*1024
constexpr size_t OFF_WZB2  = 3031392;    // 184320 shorts = 92160 floats
// total ~3,123,552 floats = 12.5 MB

__device__ inline unsigned short f2b(float x){
  union { float f; unsigned u; } a; a.f = x;
  unsigned r = a.u + 0x7fffu + ((a.u >> 16) & 1u);
  return (unsigned short)(r >> 16);
}

// ============ K1: q,k,v = x @ W^T ============
__global__ __launch_bounds__(256) void qkv_kernel(
    const float* __restrict__ x, const float* __restrict__ Wq,
    const float* __restrict__ Wk, const float* __restrict__ Wv,
    float* __restrict__ q, float* __restrict__ k, float* __restrict__ v){
  __shared__ __align__(16) float xs[8][256];
  int t = threadIdx.x;
  int i0 = blockIdx.x * 8;
  int m = blockIdx.y;
  const float* W = (m==0)?Wq:((m==1)?Wk:Wv);
  float* out = (m==0)?q:((m==1)?k:v);
  for (int idx = t; idx < 2048; idx += 256)
    xs[idx>>8][idx&255] = x[(size_t)i0*256 + idx];
  __syncthreads();
  float acc[8];
  #pragma unroll
  for (int r = 0; r < 8; r++) acc[r] = 0.f;
  const float4* wr = (const float4*)(W + (size_t)t*256);
  for (int kk = 0; kk < 64; ++kk){
    float4 w4 = wr[kk];
    #pragma unroll
    for (int r = 0; r < 8; r++){
      float4 xv = ((const float4*)xs[r])[kk];
      acc[r] += w4.x*xv.x + w4.y*xv.y + w4.z*xv.z + w4.w*xv.w;
    }
  }
  #pragma unroll
  for (int r = 0; r < 8; r++) out[(size_t)(i0+r)*256 + t] = acc[r];
}

// ============ K2: cat16 = [a_pair(8) | a_node(8)] ============
__global__ __launch_bounds__(256) void cat16_kernel(
    const float* __restrict__ z, const float* __restrict__ qb,
    const float* __restrict__ kb, const float* __restrict__ Wp2a,
    float* __restrict__ cat16){
  __shared__ float zs[32*128];
  __shared__ float wsm[8*128];
  __shared__ float qs[256];
  __shared__ float ks[32*256];
  int t = threadIdx.x;
  int pix0 = blockIdx.x * 32;
  int i = pix0 >> 8;
  int j0 = pix0 & 255;
  for (int idx = t; idx < 8*128; idx += 256) wsm[idx] = Wp2a[idx];
  qs[t] = qb[i*NDIM + t];
  for (int idx = t; idx < 32*128; idx += 256) zs[idx] = z[(size_t)pix0*128 + idx];
  for (int idx = t; idx < 32*256; idx += 256) ks[idx] = kb[(size_t)j0*NDIM + idx];
  __syncthreads();
  int p8 = t >> 3, h = t & 7;
  const float* zp = zs + p8*128;
  const float* wp = wsm + h*128;
  float ap = 0.f;
  #pragma unroll 8
  for (int p = 0; p < 128; p++) ap += zp[p]*wp[p];
  const float* qh = qs + h*32;
  const float* kh_ = ks + p8*256 + h*32;
  float an = 0.f;
  #pragma unroll
  for (int d = 0; d < HDIM; d++) an += qh[d]*kh_[d];
  an *= 0.17677669529663689f;
  int pix = pix0 + p8;
  cat16[(size_t)pix*16 + h] = ap;
  cat16[(size_t)pix*16 + 8 + h] = an;
}

// ============ coalesced two-stage instance-norm stats ============
__global__ __launch_bounds__(256) void statsA_z_kernel(
    const float* __restrict__ z, float* __restrict__ part, float* __restrict__ part2){
  __shared__ float4 sm[256], sq[256];
  int t = threadIdx.x, b = blockIdx.x;
  int c4 = t & 31, po = t >> 5;
  float4 s = {0,0,0,0}, q = {0,0,0,0};
  for (int g = 0; g < 8; ++g){
    int px = b*64 + po + g*8;
    float4 v = *(const float4*)(z + (size_t)px*128 + c4*4);
    s.x += v.x; s.y += v.y; s.z += v.z; s.w += v.w;
    q.x += v.x*v.x; q.y += v.y*v.y; q.z += v.z*v.z; q.w += v.w*v.w;
  }
  sm[t] = s; sq[t] = q;
  __syncthreads();
  if (t < 32){
    float4 S = sm[t], Q = sq[t];
    for (int p2 = 1; p2 < 8; ++p2){
      float4 a = sm[p2*32 + t], c = sq[p2*32 + t];
      S.x += a.x; S.y += a.y; S.z += a.z; S.w += a.w;
      Q.x += c.x; Q.y += c.y; Q.z += c.z; Q.w += c.w;
    }
    part [(size_t)(t*4+0)*1024 + b] = S.x; part [(size_t)(t*4+1)*1024 + b] = S.y;
    part [(size_t)(t*4+2)*1024 + b] = S.z; part [(size_t)(t*4+3)*1024 + b] = S.w;
    part2[(size_t)(t*4+0)*1024 + b] = Q.x; part2[(size_t)(t*4+1)*1024 + b] = Q.y;
    part2[(size_t)(t*4+2)*1024 + b] = Q.z; part2[(size_t)(t*4+3)*1024 + b] = Q.w;
  }
}

__global__ __launch_bounds__(256) void statsA_16_kernel(
    const float* __restrict__ src, float* __restrict__ part, float* __restrict__ part2){
  __shared__ float4 sm[256], sq[256];
  int t = threadIdx.x, b = blockIdx.x;
  int c4 = t & 3, po = t >> 2;
  float4 s = {0,0,0,0}, q = {0,0,0,0};
  for (int g = 0; g < 4; ++g){
    int px = b*256 + po + g*64;
    float4 v = *(const float4*)(src + (size_t)px*16 + c4*4);
    s.x += v.x; s.y += v.y; s.z += v.z; s.w += v.w;
    q.x += v.x*v.x; q.y += v.y*v.y; q.z += v.z*v.z; q.w += v.w*v.w;
  }
  sm[t] = s; sq[t] = q;
  __syncthreads();
  if (t < 4){
    float4 S = sm[t], Q = sq[t];
    for (int p2 = 1; p2 < 64; ++p2){
      float4 a = sm[p2*4 + t], c = sq[p2*4 + t];
      S.x += a.x; S.y += a.y; S.z += a.z; S.w += a.w;
      Q.x += c.x; Q.y += c.y; Q.z += c.z; Q.w += c.w;
    }
    part [(size_t)(t*4+0)*1024 + b] = S.x; part [(size_t)(t*4+1)*1024 + b] = S.y;
    part [(size_t)(t*4+2)*1024 + b] = S.z; part [(size_t)(t*4+3)*1024 + b] = S.w;
    part2[(size_t)(t*4+0)*1024 + b] = Q.x; part2[(size_t)(t*4+1)*1024 + b] = Q.y;
    part2[(size_t)(t*4+2)*1024 + b] = Q.z; part2[(size_t)(t*4+3)*1024 + b] = Q.w;
  }
}

__global__ __launch_bounds__(256) void statsA_s8_kernel(
    const float* __restrict__ src, float* __restrict__ part, float* __restrict__ part2,
    int coff){
  __shared__ float sm[256], sq[256];
  int t = threadIdx.x, b = blockIdx.x;
  int ch = t & 7, po = t >> 3;
  float s = 0.f, q = 0.f;
  for (int g = 0; g < 8; ++g){
    int px = b*256 + po + g*32;
    float v = src[(size_t)px*8 + ch];
    s += v; q += v*v;
  }
  sm[t] = s; sq[t] = q;
  __syncthreads();
  if (t < 8){
    float S = 0.f, Q = 0.f;
    for (int p2 = 0; p2 < 32; ++p2){ S += sm[p2*8 + t]; Q += sq[p2*8 + t]; }
    part [(size_t)(coff+t)*1024 + b] = S;
    part2[(size_t)(coff+t)*1024 + b] = Q;
  }
}

__device__ inline void block_reduce2(float& s, float& s2, float* red){
  int t = threadIdx.x;
  int lane = t & 63, wv = t >> 6;
  #pragma unroll
  for (int o = 32; o > 0; o >>= 1){ s += __shfl_down(s, o); s2 += __shfl_down(s2, o); }
  __syncthreads();
  if (lane == 0){ red[wv] = s; red[4+wv] = s2; }
  __syncthreads();
  s  = red[0]+red[1]+red[2]+red[3];
  s2 = red[4]+red[5]+red[6]+red[7];
}

__global__ __launch_bounds__(256) void statsA_s1_kernel(
    const float* __restrict__ src, float* __restrict__ part, float* __restrict__ part2,
    int coff){
  __shared__ float red[8];
  int t = threadIdx.x, b = blockIdx.x;
  float v = src[(size_t)b*256 + t];
  float s = v, q = v*v;
  block_reduce2(s, q, red);
  if (t == 0){ part[(size_t)coff*1024 + b] = s; part2[(size_t)coff*1024 + b] = q; }
}

__global__ __launch_bounds__(256) void statsB_kernel(
    const float* __restrict__ part, const float* __restrict__ part2,
    float* __restrict__ st, int C, int csplit, int nb_main, int nb_tail){
  __shared__ float red[8];
  int c = blockIdx.x, t = threadIdx.x;
  int nb = (c < csplit) ? nb_main : nb_tail;
  float s = 0.f, q = 0.f;
  for (int i = t; i < nb; i += 256){ s += part[(size_t)c*1024 + i]; q += part2[(size_t)c*1024 + i]; }
  block_reduce2(s, q, red);
  if (t == 0){
    float m = s * (1.f/NPIX);
    float var = q * (1.f/NPIX) - m*m;
    st[c] = m;
    st[C + c] = rsqrtf(var + 1e-5f);
  }
}

// ============ small conv 3x3 (CIN->COUT) fused inorm + lrelu ============
template<int CIN, int COUT>
__global__ __launch_bounds__(256) void conv_small_kernel(
    const float* __restrict__ A, int Ca, const float* __restrict__ B, int Cb,
    const float* __restrict__ st, const float* __restrict__ w,
    const float* __restrict__ bias, float* __restrict__ out){
  __shared__ float xn[3][256][CIN];
  __shared__ float wsm[COUT*CIN*9];
  __shared__ float ms[CIN], isd[CIN], bs[COUT];
  int i = blockIdx.x, t = threadIdx.x;
  if (t < CIN){ ms[t] = st[t]; isd[t] = st[CIN + t]; }
  if (t < COUT) bs[t] = bias[t];
  for (int idx = t; idx < COUT*CIN*9; idx += 256) wsm[idx] = w[idx];
  __syncthreads();
  for (int r = 0; r < 3; r++){
    int row = i - 1 + r;
    for (int idx = t; idx < 256*CIN; idx += 256){
      int col = idx / CIN, c = idx - col*CIN;
      float vv = 0.f;
      if (row >= 0 && row < 256){
        size_t pix = (size_t)row*256 + col;
        float raw = (c < Ca) ? A[pix*Ca + c] : B[pix*Cb + (c - Ca)];
        vv = (raw - ms[c]) * isd[c];
      }
      xn[r][col][c] = vv;
    }
  }
  __syncthreads();
  int j = t;
  float acc[COUT];
  #pragma unroll
  for (int o = 0; o < COUT; o++) acc[o] = bs[o];
  #pragma unroll
  for (int kh = 0; kh < 3; kh++){
    #pragma unroll
    for (int kw = 0; kw < 3; kw++){
      int jj = j + kw - 1;
      if (jj < 0 || jj > 255) continue;
      float vreg[CIN];
      #pragma unroll
      for (int c = 0; c < CIN; c++) vreg[c] = xn[kh][jj][c];
      #pragma unroll
      for (int o = 0; o < COUT; o++){
        float a = 0.f;
        #pragma unroll
        for (int c = 0; c < CIN; c++) a += vreg[c]*wsm[((o*CIN + c)*3 + kh)*3 + kw];
        acc[o] += a;
      }
    }
  }
  #pragma unroll
  for (int o = 0; o < COUT; o++){
    float vv = acc[o];
    out[((size_t)(i*256 + j))*COUT + o] = (vv >= 0.f) ? vv : 0.01f*vv;
  }
}

// ============ aggregation (512 thr, split-j) ============
__global__ __launch_bounds__(512) void agg_kernel2(
    const float* __restrict__ alpha, const float* __restrict__ z,
    const float* __restrict__ v, float* __restrict__ agg){
  __shared__ float as[2048];
  __shared__ float pp[256][4];
  __shared__ float np[256];
  int i = blockIdx.x, t = threadIdx.x;
  for (int idx = t; idx < 2048; idx += 512) as[idx] = alpha[(size_t)i*2048 + idx];
  __syncthreads();
  int tt = t & 255, jh = t >> 8;
  int p = tt & 127, hh = tt >> 7;
  const float* zrow = z + (size_t)i*32768 + (size_t)jh*128*128;
  const float* ar0 = as + jh*128*8;
  float a0=0.f, a1=0.f, a2=0.f, a3=0.f;
  for (int j = 0; j < 128; ++j){
    float zv = zrow[j*128 + p];
    const float* ar = ar0 + j*8 + hh*4;
    a0 += ar[0]*zv; a1 += ar[1]*zv; a2 += ar[2]*zv; a3 += ar[3]*zv;
  }
  int h = tt >> 5;
  float an = 0.f;
  const float* vrow = v + (size_t)jh*128*256;
  const float* ah0 = as + jh*128*8;
  for (int j = 0; j < 128; ++j) an += ah0[j*8 + h]*vrow[j*256 + tt];
  if (jh == 1){
    pp[tt][0]=a0; pp[tt][1]=a1; pp[tt][2]=a2; pp[tt][3]=a3; np[tt]=an;
  }
  __syncthreads();
  if (jh == 0){
    a0 += pp[tt][0]; a1 += pp[tt][1]; a2 += pp[tt][2]; a3 += pp[tt][3];
    an += np[tt];
    size_t ob = (size_t)i*1280;
    agg[ob + (hh*4+0)*128 + p] = a0;
    agg[ob + (hh*4+1)*128 + p] = a1;
    agg[ob + (hh*4+2)*128 + p] = a2;
    agg[ob + (hh*4+3)*128 + p] = a3;
    agg[ob + 1024 + tt] = an;
  }
}

// ============ out_transform ============
__global__ __launch_bounds__(256) void outA_kernel(
    const float* __restrict__ agg,
    const float* __restrict__ ln1_g, const float* __restrict__ ln1_b,
    const float* __restrict__ lin1_w, const float* __restrict__ lin1_b,
    float* __restrict__ y){
  __shared__ __align__(16) float h1[8][1280];
  __shared__ float red[8];
  int t = threadIdx.x;
  int rb = blockIdx.x >> 2, ob = blockIdx.x & 3;
  for (int r = 0; r < 8; ++r){
    int i = rb*8 + r;
    float v[5], s = 0.f, s2 = 0.f;
    #pragma unroll
    for (int qq = 0; qq < 5; ++qq){
      v[qq] = agg[(size_t)i*1280 + qq*256 + t];
      s += v[qq]; s2 += v[qq]*v[qq];
    }
    block_reduce2(s, s2, red);
    float m = s*(1.f/1280.f), istd = rsqrtf(s2*(1.f/1280.f) - m*m + 1e-5f);
    #pragma unroll
    for (int qq = 0; qq < 5; ++qq){
      int kk = qq*256 + t;
      h1[r][kk] = (v[qq] - m)*istd*ln1_g[kk] + ln1_b[kk];
    }
  }
  __syncthreads();
  int o = ob*128 + (t & 127);
  int half = t >> 7;
  float a0=0.f, a1=0.f, a2=0.f, a3=0.f;
  const float4* wr = (const float4*)(lin1_w + (size_t)o*1280);
  const float4* r0 = (const float4*)h1[half*4+0];
  const float4* r1 = (const float4*)h1[half*4+1];
  const float4* r2 = (const float4*)h1[half*4+2];
  const float4* r3 = (const float4*)h1[half*4+3];
  for (int kk = 0; kk < 320; ++kk){
    float4 w4 = wr[kk];
    float4 x0 = r0[kk]; a0 += w4.x*x0.x + w4.y*x0.y + w4.z*x0.z + w4.w*x0.w;
    float4 x1 = r1[kk]; a1 += w4.x*x1.x + w4.y*x1.y + w4.z*x1.z + w4.w*x1.w;
    float4 x2 = r2[kk]; a2 += w4.x*x2.x + w4.y*x2.y + w4.z*x2.z + w4.w*x2.w;
    float4 x3 = r3[kk]; a3 += w4.x*x3.x + w4.y*x3.y + w4.z*x3.z + w4.w*x3.w;
  }
  int i0 = rb*8 + half*4;
  float bb = lin1_b[o];
  y[(size_t)(i0+0)*512 + o] = a0 + bb;
  y[(size_t)(i0+1)*512 + o] = a1 + bb;
  y[(size_t)(i0+2)*512 + o] = a2 + bb;
  y[(size_t)(i0+3)*512 + o] = a3 + bb;
}

__global__ __launch_bounds__(256) void outB_kernel(
    const float* __restrict__ y, const float* __restrict__ x,
    const float* __restrict__ ln2_g, const float* __restrict__ ln2_b,
    const float* __restrict__ lin2_w, const float* __restrict__ lin2_b,
    const float* __restrict__ lnf_g, const float* __restrict__ lnf_b,
    float* __restrict__ xout){
  __shared__ __align__(16) float h2[8][512];
  __shared__ float red[8];
  int t = threadIdx.x;
  int rb = blockIdx.x;
  for (int r = 0; r < 8; ++r){
    int i = rb*8 + r;
    float y0 = y[(size_t)i*512 + t], y1 = y[(size_t)i*512 + 256 + t];
    float s = y0 + y1, s2 = y0*y0 + y1*y1;
    block_reduce2(s, s2, red);
    float m = s*(1.f/512.f), istd = rsqrtf(s2*(1.f/512.f) - m*m + 1e-5f);
    float z0 = (y0 - m)*istd*ln2_g[t] + ln2_b[t];
    float z1 = (y1 - m)*istd*ln2_g[t+256] + ln2_b[t+256];
    h2[r][t]     = (z0 >= 0.f) ? z0 : 0.01f*z0;
    h2[r][t+256] = (z1 >= 0.f) ? z1 : 0.01f*z1;
  }
  __syncthreads();
  float acc[8];
  #pragma unroll
  for (int r = 0; r < 8; ++r) acc[r] = 0.f;
  const float4* wr = (const float4*)(lin2_w + (size_t)t*512);
  for (int kk = 0; kk < 128; ++kk){
    float4 w4 = wr[kk];
    #pragma unroll
    for (int r = 0; r < 8; ++r){
      float4 h = ((const float4*)h2[r])[kk];
      acc[r] += w4.x*h.x + w4.y*h.y + w4.z*h.z + w4.w*h.w;
    }
  }
  float bb = lin2_b[t];
  for (int r = 0; r < 8; ++r){
    int i = rb*8 + r;
    float xr = x[(size_t)i*256 + t] + acc[r] + bb;
    float s = xr, s2 = xr*xr;
    block_reduce2(s, s2, red);
    float m = s*(1.f/256.f), istd = rsqrtf(s2*(1.f/256.f) - m*m + 1e-5f);
    xout[(size_t)i*256 + t] = (xr - m)*istd*lnf_g[t] + lnf_b[t];
  }
}

// ============ conv_z weight pack: B-fragments [ocb][tap][k][lane][8] ============
__global__ __launch_bounds__(256) void wz_prep2(const float* __restrict__ w,
                                                unsigned short* __restrict__ wzb2){
  int idx = blockIdx.x*256 + threadIdx.x;
  if (idx >= 23040) return;
  int lane = idx & 63;
  int f = idx >> 6;
  int k = f % 5; int ft = f / 5; int tap = ft % 9; int ocb = ft / 9;
  int oc = ocb*16 + (lane & 15);
  int chb = k*32 + (lane >> 4)*8;
  unsigned short u[8];
  #pragma unroll
  for (int j = 0; j < 8; ++j){
    int ch = chb + j;
    float vv = (ch < 136) ? w[(size_t)oc*1224 + ch*9 + tap] : 0.f;
    u[j] = f2b(vv);
  }
  uint4 pk;
  pk.x = (unsigned)u[0] | ((unsigned)u[1]<<16);
  pk.y = (unsigned)u[2] | ((unsigned)u[3]<<16);
  pk.z = (unsigned)u[4] | ((unsigned)u[5]<<16);
  pk.w = (unsigned)u[6] | ((unsigned)u[7]<<16);
  *(uint4*)(wzb2 + (size_t)idx*8) = pk;
}

// ============ conv_z v3: 6-row LDS slab, weights-per-tap in regs, no spills ====
// grid 512: stripe = bid&7 (32 cols), rowgroup = bid>>3 (4 rows)
// 4 waves; wave w owns oc [32w, 32w+32)
__global__ __launch_bounds__(256) void conv_z3_kernel(
    const float* __restrict__ z, const float* __restrict__ alpha,
    const float* __restrict__ st, const unsigned short* __restrict__ wzb2,
    const float* __restrict__ bias, float* __restrict__ out){
  __shared__ __align__(16) unsigned short xs[6*578*8];   // 55,488 B
  __shared__ __align__(16) float out32[32*132];          // 16,896 B
  __shared__ float msld[136], isdld[136];
  int t = threadIdx.x;
  int stripe = blockIdx.x & 7, rg = blockIdx.x >> 3;
  int i0 = rg*4, c0 = stripe*32;
  int lane = t & 63, w = t >> 6;
  int li = lane & 15, lg = lane >> 4;
  int wocb = w*2;
  if (t < 136){ msld[t] = st[t]; isdld[t] = st[136 + t]; }
  __syncthreads();
  // stage 6 input rows (i0-1 .. i0+4), normalized bf16, chunk layout [s][col*17+cq]
  for (int s = 0; s < 6; ++s){
    int ir = i0 - 1 + s;
    #pragma unroll
    for (int it = 0; it < 3; ++it){
      int cidx = t + it*256;
      if (cidx >= 578) continue;
      int col = cidx / 17, cq = cidx - col*17;
      int gcol = c0 + col - 1;
      uint4 pk = {0u,0u,0u,0u};
      if (ir >= 0 && ir < 256 && gcol >= 0 && gcol < 256){
        const float* src = (cq < 16) ? (z + ((size_t)ir*256 + gcol)*128 + cq*8)
                                     : (alpha + ((size_t)ir*256 + gcol)*8);
        float4 r0 = *(const float4*)src;
        float4 r1 = *(const float4*)(src + 4);
        int ch = cq*8;
        unsigned short u0 = f2b((r0.x - msld[ch+0])*isdld[ch+0]);
        unsigned short u1 = f2b((r0.y - msld[ch+1])*isdld[ch+1]);
        unsigned short u2 = f2b((r0.z - msld[ch+2])*isdld[ch+2]);
        unsigned short u3 = f2b((r0.w - msld[ch+3])*isdld[ch+3]);
        unsigned short u4 = f2b((r1.x - msld[ch+4])*isdld[ch+4]);
        unsigned short u5 = f2b((r1.y - msld[ch+5])*isdld[ch+5]);
        unsigned short u6 = f2b((r1.z - msld[ch+6])*isdld[ch+6]);
        unsigned short u7 = f2b((r1.w - msld[ch+7])*isdld[ch+7]);
        pk.x = (unsigned)u0 | ((unsigned)u1<<16);
        pk.y = (unsigned)u2 | ((unsigned)u3<<16);
        pk.z = (unsigned)u4 | ((unsigned)u5<<16);
        pk.w = (unsigned)u6 | ((unsigned)u7<<16);
      }
      *(uint4*)(xs + ((size_t)(s*578 + cidx))*8) = pk;
    }
  }
  __syncthreads();

  f32x4 acc[4][2][2];
  #pragma unroll
  for (int r = 0; r < 4; ++r)
    #pragma unroll
    for (int m = 0; m < 2; ++m)
      #pragma unroll
      for (int o = 0; o < 2; ++o) acc[r][m][o] = (f32x4){0.f,0.f,0.f,0.f};

  for (int kh = 0; kh < 3; ++kh){
    for (int kw = 0; kw < 3; ++kw){
      int tap = kh*3 + kw;
      bf16x8 wf[5][2];
      #pragma unroll
      for (int k = 0; k < 5; ++k)
        #pragma unroll
        for (int o = 0; o < 2; ++o)
          wf[k][o] = *(const bf16x8*)(wzb2 + (size_t)((((wocb+o)*9 + tap)*5 + k)*64 + lane)*8);
      #pragma unroll
      for (int r = 0; r < 4; ++r){
        const unsigned short* sb = xs + (size_t)(r + kh)*578*8;
        #pragma unroll
        for (int k = 0; k < 5; ++k){
          int cq = (k < 4) ? (k*4 + lg) : 16;
          bf16x8 a0 = *(const bf16x8*)(sb + ((li+kw)*17 + cq)*8);
          bf16x8 a1 = *(const bf16x8*)(sb + ((li+kw+16)*17 + cq)*8);
          acc[r][0][0] = __builtin_amdgcn_mfma_f32_16x16x32_bf16(a0, wf[k][0], acc[r][0][0], 0,0,0);
          acc[r][0][1] = __builtin_amdgcn_mfma_f32_16x16x32_bf16(a0, wf[k][1], acc[r][0][1], 0,0,0);
          acc[r][1][0] = __builtin_amdgcn_mfma_f32_16x16x32_bf16(a1, wf[k][0], acc[r][1][0], 0,0,0);
          acc[r][1][1] = __builtin_amdgcn_mfma_f32_16x16x32_bf16(a1, wf[k][1], acc[r][1][1], 0,0,0);
        }
      }
    }
  }

  float4 b4 = *(const float4*)(bias + (t & 31)*4);
  #pragma unroll
  for (int r = 0; r < 4; ++r){
    if (r > 0) __syncthreads();
    #pragma unroll
    for (int ri = 0; ri < 4; ++ri){
      out32[(lg*4 + ri)*132      + (wocb+0)*16 + li] = acc[r][0][0][ri];
      out32[(lg*4 + ri)*132      + (wocb+1)*16 + li] = acc[r][0][1][ri];
      out32[(16 + lg*4 + ri)*132 + (wocb+0)*16 + li] = acc[r][1][0][ri];
      out32[(16 + lg*4 + ri)*132 + (wocb+1)*16 + li] = acc[r][1][1][ri];
    }
    __syncthreads();
    int i = i0 + r;
    #pragma unroll
    for (int it = 0; it < 4; ++it){
      int px = (t >> 5) + it*8;
      float4 v = *(const float4*)(out32 + px*132 + (t & 31)*4);
      v.x += b4.x; v.y += b4.y; v.z += b4.z; v.w += b4.w;
      v.x = (v.x >= 0.f) ? v.x : 0.01f*v.x;
      v.y = (v.y >= 0.f) ? v.y : 0.01f*v.y;
      v.z = (v.z >= 0.f) ? v.z : 0.01f*v.z;
      v.w = (v.w >= 0.f) ? v.w : 0.01f*v.w;
      *(float4*)(out + ((size_t)(i*256 + c0 + px))*128 + (t & 31)*4) = v;
    }
  }
}

extern "C" void kernel_launch(void* const* d_in, const int* in_sizes, int n_in,
                              void* d_out, int out_size, void* d_ws, size_t ws_size,
                              hipStream_t stream){
  const float* x        = (const float*)d_in[0];
  const float* z        = (const float*)d_in[1];
  const float* plddt    = (const float*)d_in[2];
  const float* Wq       = (const float*)d_in[3];
  const float* Wk       = (const float*)d_in[4];
  const float* Wv       = (const float*)d_in[5];
  const float* Wp2a     = (const float*)d_in[6];
  const float* conv_a_w = (const float*)d_in[7];
  const float* conv_a_b = (const float*)d_in[8];
  const float* conv_p_w = (const float*)d_in[9];
  const float* conv_p_b = (const float*)d_in[10];
  const float* ln1_g    = (const float*)d_in[11];
  const float* ln1_b    = (const float*)d_in[12];
  const float* lin1_w   = (const float*)d_in[13];
  const float* lin1_b   = (const float*)d_in[14];
  const float* ln2_g    = (const float*)d_in[15];
  const float* ln2_b    = (const float*)d_in[16];
  const float* lin2_w   = (const float*)d_in[17];
  const float* lin2_b   = (const float*)d_in[18];
  const float* lnf_g    = (const float*)d_in[19];
  const float* lnf_b    = (const float*)d_in[20];
  const float* conv_z_w = (const float*)d_in[21];
  const float* conv_z_b = (const float*)d_in[22];

  float* ws    = (float*)d_ws;
  float* q     = ws + OFF_Q;
  float* k     = ws + OFF_K;
  float* v     = ws + OFF_V;
  float* cat16 = ws + OFF_CAT16;
  float* a1    = ws + OFF_A1;
  float* alpha = ws + OFF_ALPHA;
  float* agg   = ws + OFF_AGG;
  float* y     = ws + OFF_Y;
  float* st16  = ws + OFF_ST16;
  float* st9   = ws + OFF_ST9;
  float* st136 = ws + OFF_ST136;
  float* part  = ws + OFF_PART;
  float* part2 = ws + OFF_PART2;
  unsigned short* wzb2 = (unsigned short*)(ws + OFF_WZB2);

  float* xout = (float*)d_out;
  float* zout = (float*)d_out + 65536;

  qkv_kernel<<<dim3(32,3), 256, 0, stream>>>(x, Wq, Wk, Wv, q, k, v);
  cat16_kernel<<<2048, 256, 0, stream>>>(z, q, k, Wp2a, cat16);
  statsA_16_kernel<<<256, 256, 0, stream>>>(cat16, part, part2);
  statsB_kernel<<<16, 256, 0, stream>>>(part, part2, st16, 16, 16, 256, 256);
  conv_small_kernel<16,8><<<256, 256, 0, stream>>>(cat16, 16, (const float*)nullptr, 0,
                                                   st16, conv_a_w, conv_a_b, a1);
  statsA_s8_kernel<<<256, 256, 0, stream>>>(a1, part, part2, 0);
  statsA_s1_kernel<<<256, 256, 0, stream>>>(plddt, part, part2, 8);
  statsB_kernel<<<9, 256, 0, stream>>>(part, part2, st9, 9, 9, 256, 256);
  conv_small_kernel<9,8><<<256, 256, 0, stream>>>(a1, 8, plddt, 1,
                                                  st9, conv_p_w, conv_p_b, alpha);
  agg_kernel2<<<256, 512, 0, stream>>>(alpha, z, v, agg);
  outA_kernel<<<128, 256, 0, stream>>>(agg, ln1_g, ln1_b, lin1_w, lin1_b, y);
  outB_kernel<<<32, 256, 0, stream>>>(y, x, ln2_g, ln2_b, lin2_w, lin2_b,
                                      lnf_g, lnf_b, xout);
  statsA_z_kernel<<<1024, 256, 0, stream>>>(z, part, part2);
  statsA_s8_kernel<<<256, 256, 0, stream>>>(alpha, part, part2, 128);
  statsB_kernel<<<136, 256, 0, stream>>>(part, part2, st136, 136, 128, 1024, 256);
  wz_prep2<<<90, 256, 0, stream>>>(conv_z_w, wzb2);
  conv_z3_kernel<<<512, 256, 0, stream>>>(z, alpha, st136, wzb2, conv_z_b, zout);
}

// Round 7
// 258.983 us; speedup vs baseline: 2.8260x; 1.1273x over previous
//
#include <hip/hip_runtime.h>
#include <math.h>

#define LLEN 256
#define NDIM 256
#define NHEAD 8
#define HDIM 32
#define NPIX (LLEN*LLEN)

typedef __bf16 bf16x8 __attribute__((ext_vector_type(8)));
typedef float f32x4 __attribute__((ext_vector_type(4)));

// ---- workspace layout (float offsets) ----
constexpr size_t OFF_Q     = 0;          // 65536
constexpr size_t OFF_K     = 65536;
constexpr size_t OFF_V     = 131072;
constexpr size_t OFF_CAT16 = 196608;     // 1048576 (dead after conv_small<16,8>)
constexpr size_t OFF_H1B   = 196608;     // 163840 floats as bf16 h1 (reuses cat16)
constexpr size_t OFF_W1B   = 360448;     // 327680 floats as bf16 lin1_w (reuses cat16)
constexpr size_t OFF_A1    = 1245184;    // 524288
constexpr size_t OFF_ALPHA = 1769472;    // 524288
constexpr size_t OFF_AGG   = 2293760;    // 327680
constexpr size_t OFF_Y     = 2621440;    // 131072
constexpr size_t OFF_ST16  = 2752512;    // 32
constexpr size_t OFF_ST9   = 2752544;    // 32
constexpr size_t OFF_ST136 = 2752576;    // 288
constexpr size_t OFF_PART  = 2752864;    // 136*1024
constexpr size_t OFF_PART2 = 2892128;    // 136*1024
constexpr size_t OFF_WZB2  = 3031392;    // 184320 shorts = 92160 floats
// total ~3,123,552 floats = 12.5 MB

__device__ inline unsigned short f2b(float x){
  union { float f; unsigned u; } a; a.f = x;
  unsigned r = a.u + 0x7fffu + ((a.u >> 16) & 1u);
  return (unsigned short)(r >> 16);
}

// ============ K1: q,k,v = x @ W^T ============
__global__ __launch_bounds__(256) void qkv_kernel(
    const float* __restrict__ x, const float* __restrict__ Wq,
    const float* __restrict__ Wk, const float* __restrict__ Wv,
    float* __restrict__ q, float* __restrict__ k, float* __restrict__ v){
  __shared__ __align__(16) float xs[8][256];
  int t = threadIdx.x;
  int i0 = blockIdx.x * 8;
  int m = blockIdx.y;
  const float* W = (m==0)?Wq:((m==1)?Wk:Wv);
  float* out = (m==0)?q:((m==1)?k:v);
  for (int idx = t; idx < 2048; idx += 256)
    xs[idx>>8][idx&255] = x[(size_t)i0*256 + idx];
  __syncthreads();
  float acc[8];
  #pragma unroll
  for (int r = 0; r < 8; r++) acc[r] = 0.f;
  const float4* wr = (const float4*)(W + (size_t)t*256);
  for (int kk = 0; kk < 64; ++kk){
    float4 w4 = wr[kk];
    #pragma unroll
    for (int r = 0; r < 8; r++){
      float4 xv = ((const float4*)xs[r])[kk];
      acc[r] += w4.x*xv.x + w4.y*xv.y + w4.z*xv.z + w4.w*xv.w;
    }
  }
  #pragma unroll
  for (int r = 0; r < 8; r++) out[(size_t)(i0+r)*256 + t] = acc[r];
}

// ============ K2: cat16 = [a_pair(8) | a_node(8)] ============
__global__ __launch_bounds__(256) void cat16_kernel(
    const float* __restrict__ z, const float* __restrict__ qb,
    const float* __restrict__ kb, const float* __restrict__ Wp2a,
    float* __restrict__ cat16){
  __shared__ float zs[32*128];
  __shared__ float wsm[8*128];
  __shared__ float qs[256];
  __shared__ float ks[32*256];
  int t = threadIdx.x;
  int pix0 = blockIdx.x * 32;
  int i = pix0 >> 8;
  int j0 = pix0 & 255;
  for (int idx = t; idx < 8*128; idx += 256) wsm[idx] = Wp2a[idx];
  qs[t] = qb[i*NDIM + t];
  for (int idx = t; idx < 32*128; idx += 256) zs[idx] = z[(size_t)pix0*128 + idx];
  for (int idx = t; idx < 32*256; idx += 256) ks[idx] = kb[(size_t)j0*NDIM + idx];
  __syncthreads();
  int p8 = t >> 3, h = t & 7;
  const float* zp = zs + p8*128;
  const float* wp = wsm + h*128;
  float ap = 0.f;
  #pragma unroll 8
  for (int p = 0; p < 128; p++) ap += zp[p]*wp[p];
  const float* qh = qs + h*32;
  const float* kh_ = ks + p8*256 + h*32;
  float an = 0.f;
  #pragma unroll
  for (int d = 0; d < HDIM; d++) an += qh[d]*kh_[d];
  an *= 0.17677669529663689f;
  int pix = pix0 + p8;
  cat16[(size_t)pix*16 + h] = ap;
  cat16[(size_t)pix*16 + 8 + h] = an;
}

// ============ coalesced two-stage instance-norm stats ============
__global__ __launch_bounds__(256) void statsA_z_kernel(
    const float* __restrict__ z, float* __restrict__ part, float* __restrict__ part2){
  __shared__ float4 sm[256], sq[256];
  int t = threadIdx.x, b = blockIdx.x;
  int c4 = t & 31, po = t >> 5;
  float4 s = {0,0,0,0}, q = {0,0,0,0};
  for (int g = 0; g < 8; ++g){
    int px = b*64 + po + g*8;
    float4 v = *(const float4*)(z + (size_t)px*128 + c4*4);
    s.x += v.x; s.y += v.y; s.z += v.z; s.w += v.w;
    q.x += v.x*v.x; q.y += v.y*v.y; q.z += v.z*v.z; q.w += v.w*v.w;
  }
  sm[t] = s; sq[t] = q;
  __syncthreads();
  if (t < 32){
    float4 S = sm[t], Q = sq[t];
    for (int p2 = 1; p2 < 8; ++p2){
      float4 a = sm[p2*32 + t], c = sq[p2*32 + t];
      S.x += a.x; S.y += a.y; S.z += a.z; S.w += a.w;
      Q.x += c.x; Q.y += c.y; Q.z += c.z; Q.w += c.w;
    }
    part [(size_t)(t*4+0)*1024 + b] = S.x; part [(size_t)(t*4+1)*1024 + b] = S.y;
    part [(size_t)(t*4+2)*1024 + b] = S.z; part [(size_t)(t*4+3)*1024 + b] = S.w;
    part2[(size_t)(t*4+0)*1024 + b] = Q.x; part2[(size_t)(t*4+1)*1024 + b] = Q.y;
    part2[(size_t)(t*4+2)*1024 + b] = Q.z; part2[(size_t)(t*4+3)*1024 + b] = Q.w;
  }
}

__global__ __launch_bounds__(256) void statsA_16_kernel(
    const float* __restrict__ src, float* __restrict__ part, float* __restrict__ part2){
  __shared__ float4 sm[256], sq[256];
  int t = threadIdx.x, b = blockIdx.x;
  int c4 = t & 3, po = t >> 2;
  float4 s = {0,0,0,0}, q = {0,0,0,0};
  for (int g = 0; g < 4; ++g){
    int px = b*256 + po + g*64;
    float4 v = *(const float4*)(src + (size_t)px*16 + c4*4);
    s.x += v.x; s.y += v.y; s.z += v.z; s.w += v.w;
    q.x += v.x*v.x; q.y += v.y*v.y; q.z += v.z*v.z; q.w += v.w*v.w;
  }
  sm[t] = s; sq[t] = q;
  __syncthreads();
  if (t < 4){
    float4 S = sm[t], Q = sq[t];
    for (int p2 = 1; p2 < 64; ++p2){
      float4 a = sm[p2*4 + t], c = sq[p2*4 + t];
      S.x += a.x; S.y += a.y; S.z += a.z; S.w += a.w;
      Q.x += c.x; Q.y += c.y; Q.z += c.z; Q.w += c.w;
    }
    part [(size_t)(t*4+0)*1024 + b] = S.x; part [(size_t)(t*4+1)*1024 + b] = S.y;
    part [(size_t)(t*4+2)*1024 + b] = S.z; part [(size_t)(t*4+3)*1024 + b] = S.w;
    part2[(size_t)(t*4+0)*1024 + b] = Q.x; part2[(size_t)(t*4+1)*1024 + b] = Q.y;
    part2[(size_t)(t*4+2)*1024 + b] = Q.z; part2[(size_t)(t*4+3)*1024 + b] = Q.w;
  }
}

__global__ __launch_bounds__(256) void statsA_s8_kernel(
    const float* __restrict__ src, float* __restrict__ part, float* __restrict__ part2,
    int coff){
  __shared__ float sm[256], sq[256];
  int t = threadIdx.x, b = blockIdx.x;
  int ch = t & 7, po = t >> 3;
  float s = 0.f, q = 0.f;
  for (int g = 0; g < 8; ++g){
    int px = b*256 + po + g*32;
    float v = src[(size_t)px*8 + ch];
    s += v; q += v*v;
  }
  sm[t] = s; sq[t] = q;
  __syncthreads();
  if (t < 8){
    float S = 0.f, Q = 0.f;
    for (int p2 = 0; p2 < 32; ++p2){ S += sm[p2*8 + t]; Q += sq[p2*8 + t]; }
    part [(size_t)(coff+t)*1024 + b] = S;
    part2[(size_t)(coff+t)*1024 + b] = Q;
  }
}

__device__ inline void block_reduce2(float& s, float& s2, float* red){
  int t = threadIdx.x;
  int lane = t & 63, wv = t >> 6;
  #pragma unroll
  for (int o = 32; o > 0; o >>= 1){ s += __shfl_down(s, o); s2 += __shfl_down(s2, o); }
  __syncthreads();
  if (lane == 0){ red[wv] = s; red[4+wv] = s2; }
  __syncthreads();
  s  = red[0]+red[1]+red[2]+red[3];
  s2 = red[4]+red[5]+red[6]+red[7];
}

__global__ __launch_bounds__(256) void statsA_s1_kernel(
    const float* __restrict__ src, float* __restrict__ part, float* __restrict__ part2,
    int coff){
  __shared__ float red[8];
  int t = threadIdx.x, b = blockIdx.x;
  float v = src[(size_t)b*256 + t];
  float s = v, q = v*v;
  block_reduce2(s, q, red);
  if (t == 0){ part[(size_t)coff*1024 + b] = s; part2[(size_t)coff*1024 + b] = q; }
}

__global__ __launch_bounds__(256) void statsB_kernel(
    const float* __restrict__ part, const float* __restrict__ part2,
    float* __restrict__ st, int C, int csplit, int nb_main, int nb_tail){
  __shared__ float red[8];
  int c = blockIdx.x, t = threadIdx.x;
  int nb = (c < csplit) ? nb_main : nb_tail;
  float s = 0.f, q = 0.f;
  for (int i = t; i < nb; i += 256){ s += part[(size_t)c*1024 + i]; q += part2[(size_t)c*1024 + i]; }
  block_reduce2(s, q, red);
  if (t == 0){
    float m = s * (1.f/NPIX);
    float var = q * (1.f/NPIX) - m*m;
    st[c] = m;
    st[C + c] = rsqrtf(var + 1e-5f);
  }
}

// ============ small conv 3x3 (CIN->COUT) fused inorm + lrelu ============
template<int CIN, int COUT>
__global__ __launch_bounds__(256) void conv_small_kernel(
    const float* __restrict__ A, int Ca, const float* __restrict__ B, int Cb,
    const float* __restrict__ st, const float* __restrict__ w,
    const float* __restrict__ bias, float* __restrict__ out){
  __shared__ float xn[3][256][CIN];
  __shared__ float wsm[COUT*CIN*9];
  __shared__ float ms[CIN], isd[CIN], bs[COUT];
  int i = blockIdx.x, t = threadIdx.x;
  if (t < CIN){ ms[t] = st[t]; isd[t] = st[CIN + t]; }
  if (t < COUT) bs[t] = bias[t];
  for (int idx = t; idx < COUT*CIN*9; idx += 256) wsm[idx] = w[idx];
  __syncthreads();
  for (int r = 0; r < 3; r++){
    int row = i - 1 + r;
    for (int idx = t; idx < 256*CIN; idx += 256){
      int col = idx / CIN, c = idx - col*CIN;
      float vv = 0.f;
      if (row >= 0 && row < 256){
        size_t pix = (size_t)row*256 + col;
        float raw = (c < Ca) ? A[pix*Ca + c] : B[pix*Cb + (c - Ca)];
        vv = (raw - ms[c]) * isd[c];
      }
      xn[r][col][c] = vv;
    }
  }
  __syncthreads();
  int j = t;
  float acc[COUT];
  #pragma unroll
  for (int o = 0; o < COUT; o++) acc[o] = bs[o];
  #pragma unroll
  for (int kh = 0; kh < 3; kh++){
    #pragma unroll
    for (int kw = 0; kw < 3; kw++){
      int jj = j + kw - 1;
      if (jj < 0 || jj > 255) continue;
      float vreg[CIN];
      #pragma unroll
      for (int c = 0; c < CIN; c++) vreg[c] = xn[kh][jj][c];
      #pragma unroll
      for (int o = 0; o < COUT; o++){
        float a = 0.f;
        #pragma unroll
        for (int c = 0; c < CIN; c++) a += vreg[c]*wsm[((o*CIN + c)*3 + kh)*3 + kw];
        acc[o] += a;
      }
    }
  }
  #pragma unroll
  for (int o = 0; o < COUT; o++){
    float vv = acc[o];
    out[((size_t)(i*256 + j))*COUT + o] = (vv >= 0.f) ? vv : 0.01f*vv;
  }
}

// ============ aggregation (512 thr, split-j) ============
__global__ __launch_bounds__(512) void agg_kernel2(
    const float* __restrict__ alpha, const float* __restrict__ z,
    const float* __restrict__ v, float* __restrict__ agg){
  __shared__ float as[2048];
  __shared__ float pp[256][4];
  __shared__ float np[256];
  int i = blockIdx.x, t = threadIdx.x;
  for (int idx = t; idx < 2048; idx += 512) as[idx] = alpha[(size_t)i*2048 + idx];
  __syncthreads();
  int tt = t & 255, jh = t >> 8;
  int p = tt & 127, hh = tt >> 7;
  const float* zrow = z + (size_t)i*32768 + (size_t)jh*128*128;
  const float* ar0 = as + jh*128*8;
  float a0=0.f, a1=0.f, a2=0.f, a3=0.f;
  for (int j = 0; j < 128; ++j){
    float zv = zrow[j*128 + p];
    const float* ar = ar0 + j*8 + hh*4;
    a0 += ar[0]*zv; a1 += ar[1]*zv; a2 += ar[2]*zv; a3 += ar[3]*zv;
  }
  int h = tt >> 5;
  float an = 0.f;
  const float* vrow = v + (size_t)jh*128*256;
  const float* ah0 = as + jh*128*8;
  for (int j = 0; j < 128; ++j) an += ah0[j*8 + h]*vrow[j*256 + tt];
  if (jh == 1){
    pp[tt][0]=a0; pp[tt][1]=a1; pp[tt][2]=a2; pp[tt][3]=a3; np[tt]=an;
  }
  __syncthreads();
  if (jh == 0){
    a0 += pp[tt][0]; a1 += pp[tt][1]; a2 += pp[tt][2]; a3 += pp[tt][3];
    an += np[tt];
    size_t ob = (size_t)i*1280;
    agg[ob + (hh*4+0)*128 + p] = a0;
    agg[ob + (hh*4+1)*128 + p] = a1;
    agg[ob + (hh*4+2)*128 + p] = a2;
    agg[ob + (hh*4+3)*128 + p] = a3;
    agg[ob + 1024 + tt] = an;
  }
}

// ============ out_transform: LN1 -> bf16 ============
__global__ __launch_bounds__(256) void ln1_kernel(
    const float* __restrict__ agg,
    const float* __restrict__ ln1_g, const float* __restrict__ ln1_b,
    unsigned short* __restrict__ h1b){
  __shared__ float red[8];
  int i = blockIdx.x, t = threadIdx.x;
  float v[5], s = 0.f, s2 = 0.f;
  #pragma unroll
  for (int qq = 0; qq < 5; ++qq){
    v[qq] = agg[(size_t)i*1280 + qq*256 + t];
    s += v[qq]; s2 += v[qq]*v[qq];
  }
  block_reduce2(s, s2, red);
  float m = s*(1.f/1280.f), istd = rsqrtf(s2*(1.f/1280.f) - m*m + 1e-5f);
  #pragma unroll
  for (int qq = 0; qq < 5; ++qq){
    int kk = qq*256 + t;
    h1b[(size_t)i*1280 + kk] = f2b((v[qq] - m)*istd*ln1_g[kk] + ln1_b[kk]);
  }
}

// ============ lin1_w -> bf16 ============
__global__ __launch_bounds__(256) void w1_prep(const float* __restrict__ w,
                                               unsigned short* __restrict__ wb){
  int idx = (blockIdx.x*256 + threadIdx.x)*4;   // 640 blocks covers 655360
  float4 v = *(const float4*)(w + idx);
  ushort4 u;
  u.x = f2b(v.x); u.y = f2b(v.y); u.z = f2b(v.z); u.w = f2b(v.w);
  *(ushort4*)(wb + idx) = u;
}

// ============ gemm1: y[256x512] = h1b @ w1b^T + b, MFMA bf16 ============
// grid 32: mb = bid&3 (64 rows), nb = bid>>2 (64 cols); 4 waves: 32x32 each
__global__ __launch_bounds__(256) void gemm1_kernel(
    const unsigned short* __restrict__ h1b, const unsigned short* __restrict__ w1b,
    const float* __restrict__ lin1_b, float* __restrict__ y){
  int t = threadIdx.x;
  int mb = blockIdx.x & 3, nb = blockIdx.x >> 2;
  int lane = t & 63, w = t >> 6;
  int li = lane & 15, lg = lane >> 4;
  int mh = w & 1, nh = w >> 1;
  int mbase = mb*64 + mh*32, nbase = nb*64 + nh*32;
  f32x4 acc[2][2];
  #pragma unroll
  for (int a = 0; a < 2; ++a)
    #pragma unroll
    for (int b = 0; b < 2; ++b) acc[a][b] = (f32x4){0.f,0.f,0.f,0.f};
  const unsigned short* ar0 = h1b + (size_t)(mbase + li)*1280 + lg*8;
  const unsigned short* ar1 = ar0 + 16*1280;
  const unsigned short* br0 = w1b + (size_t)(nbase + li)*1280 + lg*8;
  const unsigned short* br1 = br0 + 16*1280;
  #pragma unroll 4
  for (int ks = 0; ks < 40; ++ks){
    bf16x8 a0 = *(const bf16x8*)(ar0 + ks*32);
    bf16x8 a1 = *(const bf16x8*)(ar1 + ks*32);
    bf16x8 b0 = *(const bf16x8*)(br0 + ks*32);
    bf16x8 b1 = *(const bf16x8*)(br1 + ks*32);
    acc[0][0] = __builtin_amdgcn_mfma_f32_16x16x32_bf16(a0, b0, acc[0][0], 0,0,0);
    acc[0][1] = __builtin_amdgcn_mfma_f32_16x16x32_bf16(a0, b1, acc[0][1], 0,0,0);
    acc[1][0] = __builtin_amdgcn_mfma_f32_16x16x32_bf16(a1, b0, acc[1][0], 0,0,0);
    acc[1][1] = __builtin_amdgcn_mfma_f32_16x16x32_bf16(a1, b1, acc[1][1], 0,0,0);
  }
  #pragma unroll
  for (int mi = 0; mi < 2; ++mi){
    #pragma unroll
    for (int ni = 0; ni < 2; ++ni){
      int col = nbase + ni*16 + li;
      float bb = lin1_b[col];
      #pragma unroll
      for (int ri = 0; ri < 4; ++ri){
        int row = mbase + mi*16 + lg*4 + ri;
        y[(size_t)row*512 + col] = acc[mi][ni][ri] + bb;
      }
    }
  }
}

__global__ __launch_bounds__(256) void outB_kernel(
    const float* __restrict__ y, const float* __restrict__ x,
    const float* __restrict__ ln2_g, const float* __restrict__ ln2_b,
    const float* __restrict__ lin2_w, const float* __restrict__ lin2_b,
    const float* __restrict__ lnf_g, const float* __restrict__ lnf_b,
    float* __restrict__ xout){
  __shared__ __align__(16) float h2[8][512];
  __shared__ float red[8];
  int t = threadIdx.x;
  int rb = blockIdx.x;
  for (int r = 0; r < 8; ++r){
    int i = rb*8 + r;
    float y0 = y[(size_t)i*512 + t], y1 = y[(size_t)i*512 + 256 + t];
    float s = y0 + y1, s2 = y0*y0 + y1*y1;
    block_reduce2(s, s2, red);
    float m = s*(1.f/512.f), istd = rsqrtf(s2*(1.f/512.f) - m*m + 1e-5f);
    float z0 = (y0 - m)*istd*ln2_g[t] + ln2_b[t];
    float z1 = (y1 - m)*istd*ln2_g[t+256] + ln2_b[t+256];
    h2[r][t]     = (z0 >= 0.f) ? z0 : 0.01f*z0;
    h2[r][t+256] = (z1 >= 0.f) ? z1 : 0.01f*z1;
  }
  __syncthreads();
  float acc[8];
  #pragma unroll
  for (int r = 0; r < 8; ++r) acc[r] = 0.f;
  const float4* wr = (const float4*)(lin2_w + (size_t)t*512);
  for (int kk = 0; kk < 128; ++kk){
    float4 w4 = wr[kk];
    #pragma unroll
    for (int r = 0; r < 8; ++r){
      float4 h = ((const float4*)h2[r])[kk];
      acc[r] += w4.x*h.x + w4.y*h.y + w4.z*h.z + w4.w*h.w;
    }
  }
  float bb = lin2_b[t];
  for (int r = 0; r < 8; ++r){
    int i = rb*8 + r;
    float xr = x[(size_t)i*256 + t] + acc[r] + bb;
    float s = xr, s2 = xr*xr;
    block_reduce2(s, s2, red);
    float m = s*(1.f/256.f), istd = rsqrtf(s2*(1.f/256.f) - m*m + 1e-5f);
    xout[(size_t)i*256 + t] = (xr - m)*istd*lnf_g[t] + lnf_b[t];
  }
}

// ============ conv_z weight pack: B-fragments [ocb][tap][k][lane][8] ============
__global__ __launch_bounds__(256) void wz_prep2(const float* __restrict__ w,
                                                unsigned short* __restrict__ wzb2){
  int idx = blockIdx.x*256 + threadIdx.x;
  if (idx >= 23040) return;
  int lane = idx & 63;
  int f = idx >> 6;
  int k = f % 5; int ft = f / 5; int tap = ft % 9; int ocb = ft / 9;
  int oc = ocb*16 + (lane & 15);
  int chb = k*32 + (lane >> 4)*8;
  unsigned short u[8];
  #pragma unroll
  for (int j = 0; j < 8; ++j){
    int ch = chb + j;
    float vv = (ch < 136) ? w[(size_t)oc*1224 + ch*9 + tap] : 0.f;
    u[j] = f2b(vv);
  }
  uint4 pk;
  pk.x = (unsigned)u[0] | ((unsigned)u[1]<<16);
  pk.y = (unsigned)u[2] | ((unsigned)u[3]<<16);
  pk.z = (unsigned)u[4] | ((unsigned)u[5]<<16);
  pk.w = (unsigned)u[6] | ((unsigned)u[7]<<16);
  *(uint4*)(wzb2 + (size_t)idx*8) = pk;
}

// ============ conv_z v3: 6-row LDS slab, weights-per-tap in regs ============
__global__ __launch_bounds__(256) void conv_z3_kernel(
    const float* __restrict__ z, const float* __restrict__ alpha,
    const float* __restrict__ st, const unsigned short* __restrict__ wzb2,
    const float* __restrict__ bias, float* __restrict__ out){
  __shared__ __align__(16) unsigned short xs[6*578*8];   // 55,488 B
  __shared__ __align__(16) float out32[32*132];          // 16,896 B
  __shared__ float msld[136], isdld[136];
  int t = threadIdx.x;
  int stripe = blockIdx.x & 7, rg = blockIdx.x >> 3;
  int i0 = rg*4, c0 = stripe*32;
  int lane = t & 63, w = t >> 6;
  int li = lane & 15, lg = lane >> 4;
  int wocb = w*2;
  if (t < 136){ msld[t] = st[t]; isdld[t] = st[136 + t]; }
  __syncthreads();
  for (int s = 0; s < 6; ++s){
    int ir = i0 - 1 + s;
    #pragma unroll
    for (int it = 0; it < 3; ++it){
      int cidx = t + it*256;
      if (cidx >= 578) continue;
      int col = cidx / 17, cq = cidx - col*17;
      int gcol = c0 + col - 1;
      uint4 pk = {0u,0u,0u,0u};
      if (ir >= 0 && ir < 256 && gcol >= 0 && gcol < 256){
        const float* src = (cq < 16) ? (z + ((size_t)ir*256 + gcol)*128 + cq*8)
                                     : (alpha + ((size_t)ir*256 + gcol)*8);
        float4 r0 = *(const float4*)src;
        float4 r1 = *(const float4*)(src + 4);
        int ch = cq*8;
        unsigned short u0 = f2b((r0.x - msld[ch+0])*isdld[ch+0]);
        unsigned short u1 = f2b((r0.y - msld[ch+1])*isdld[ch+1]);
        unsigned short u2 = f2b((r0.z - msld[ch+2])*isdld[ch+2]);
        unsigned short u3 = f2b((r0.w - msld[ch+3])*isdld[ch+3]);
        unsigned short u4 = f2b((r1.x - msld[ch+4])*isdld[ch+4]);
        unsigned short u5 = f2b((r1.y - msld[ch+5])*isdld[ch+5]);
        unsigned short u6 = f2b((r1.z - msld[ch+6])*isdld[ch+6]);
        unsigned short u7 = f2b((r1.w - msld[ch+7])*isdld[ch+7]);
        pk.x = (unsigned)u0 | ((unsigned)u1<<16);
        pk.y = (unsigned)u2 | ((unsigned)u3<<16);
        pk.z = (unsigned)u4 | ((unsigned)u5<<16);
        pk.w = (unsigned)u6 | ((unsigned)u7<<16);
      }
      *(uint4*)(xs + ((size_t)(s*578 + cidx))*8) = pk;
    }
  }
  __syncthreads();

  f32x4 acc[4][2][2];
  #pragma unroll
  for (int r = 0; r < 4; ++r)
    #pragma unroll
    for (int m = 0; m < 2; ++m)
      #pragma unroll
      for (int o = 0; o < 2; ++o) acc[r][m][o] = (f32x4){0.f,0.f,0.f,0.f};

  for (int kh = 0; kh < 3; ++kh){
    for (int kw = 0; kw < 3; ++kw){
      int tap = kh*3 + kw;
      bf16x8 wf[5][2];
      #pragma unroll
      for (int k = 0; k < 5; ++k)
        #pragma unroll
        for (int o = 0; o < 2; ++o)
          wf[k][o] = *(const bf16x8*)(wzb2 + (size_t)((((wocb+o)*9 + tap)*5 + k)*64 + lane)*8);
      #pragma unroll
      for (int r = 0; r < 4; ++r){
        const unsigned short* sb = xs + (size_t)(r + kh)*578*8;
        #pragma unroll
        for (int k = 0; k < 5; ++k){
          int cq = (k < 4) ? (k*4 + lg) : 16;
          bf16x8 a0 = *(const bf16x8*)(sb + ((li+kw)*17 + cq)*8);
          bf16x8 a1 = *(const bf16x8*)(sb + ((li+kw+16)*17 + cq)*8);
          acc[r][0][0] = __builtin_amdgcn_mfma_f32_16x16x32_bf16(a0, wf[k][0], acc[r][0][0], 0,0,0);
          acc[r][0][1] = __builtin_amdgcn_mfma_f32_16x16x32_bf16(a0, wf[k][1], acc[r][0][1], 0,0,0);
          acc[r][1][0] = __builtin_amdgcn_mfma_f32_16x16x32_bf16(a1, wf[k][0], acc[r][1][0], 0,0,0);
          acc[r][1][1] = __builtin_amdgcn_mfma_f32_16x16x32_bf16(a1, wf[k][1], acc[r][1][1], 0,0,0);
        }
      }
    }
  }

  float4 b4 = *(const float4*)(bias + (t & 31)*4);
  #pragma unroll
  for (int r = 0; r < 4; ++r){
    if (r > 0) __syncthreads();
    #pragma unroll
    for (int ri = 0; ri < 4; ++ri){
      out32[(lg*4 + ri)*132      + (wocb+0)*16 + li] = acc[r][0][0][ri];
      out32[(lg*4 + ri)*132      + (wocb+1)*16 + li] = acc[r][0][1][ri];
      out32[(16 + lg*4 + ri)*132 + (wocb+0)*16 + li] = acc[r][1][0][ri];
      out32[(16 + lg*4 + ri)*132 + (wocb+1)*16 + li] = acc[r][1][1][ri];
    }
    __syncthreads();
    int i = i0 + r;
    #pragma unroll
    for (int it = 0; it < 4; ++it){
      int px = (t >> 5) + it*8;
      float4 v = *(const float4*)(out32 + px*132 + (t & 31)*4);
      v.x += b4.x; v.y += b4.y; v.z += b4.z; v.w += b4.w;
      v.x = (v.x >= 0.f) ? v.x : 0.01f*v.x;
      v.y = (v.y >= 0.f) ? v.y : 0.01f*v.y;
      v.z = (v.z >= 0.f) ? v.z : 0.01f*v.z;
      v.w = (v.w >= 0.f) ? v.w : 0.01f*v.w;
      *(float4*)(out + ((size_t)(i*256 + c0 + px))*128 + (t & 31)*4) = v;
    }
  }
}

extern "C" void kernel_launch(void* const* d_in, const int* in_sizes, int n_in,
                              void* d_out, int out_size, void* d_ws, size_t ws_size,
                              hipStream_t stream){
  const float* x        = (const float*)d_in[0];
  const float* z        = (const float*)d_in[1];
  const float* plddt    = (const float*)d_in[2];
  const float* Wq       = (const float*)d_in[3];
  const float* Wk       = (const float*)d_in[4];
  const float* Wv       = (const float*)d_in[5];
  const float* Wp2a     = (const float*)d_in[6];
  const float* conv_a_w = (const float*)d_in[7];
  const float* conv_a_b = (const float*)d_in[8];
  const float* conv_p_w = (const float*)d_in[9];
  const float* conv_p_b = (const float*)d_in[10];
  const float* ln1_g    = (const float*)d_in[11];
  const float* ln1_b    = (const float*)d_in[12];
  const float* lin1_w   = (const float*)d_in[13];
  const float* lin1_b   = (const float*)d_in[14];
  const float* ln2_g    = (const float*)d_in[15];
  const float* ln2_b    = (const float*)d_in[16];
  const float* lin2_w   = (const float*)d_in[17];
  const float* lin2_b   = (const float*)d_in[18];
  const float* lnf_g    = (const float*)d_in[19];
  const float* lnf_b    = (const float*)d_in[20];
  const float* conv_z_w = (const float*)d_in[21];
  const float* conv_z_b = (const float*)d_in[22];

  float* ws    = (float*)d_ws;
  float* q     = ws + OFF_Q;
  float* k     = ws + OFF_K;
  float* v     = ws + OFF_V;
  float* cat16 = ws + OFF_CAT16;
  float* a1    = ws + OFF_A1;
  float* alpha = ws + OFF_ALPHA;
  float* agg   = ws + OFF_AGG;
  float* y     = ws + OFF_Y;
  float* st16  = ws + OFF_ST16;
  float* st9   = ws + OFF_ST9;
  float* st136 = ws + OFF_ST136;
  float* part  = ws + OFF_PART;
  float* part2 = ws + OFF_PART2;
  unsigned short* wzb2 = (unsigned short*)(ws + OFF_WZB2);
  unsigned short* h1b  = (unsigned short*)(ws + OFF_H1B);
  unsigned short* w1b  = (unsigned short*)(ws + OFF_W1B);

  float* xout = (float*)d_out;
  float* zout = (float*)d_out + 65536;

  qkv_kernel<<<dim3(32,3), 256, 0, stream>>>(x, Wq, Wk, Wv, q, k, v);
  cat16_kernel<<<2048, 256, 0, stream>>>(z, q, k, Wp2a, cat16);
  statsA_16_kernel<<<256, 256, 0, stream>>>(cat16, part, part2);
  statsB_kernel<<<16, 256, 0, stream>>>(part, part2, st16, 16, 16, 256, 256);
  conv_small_kernel<16,8><<<256, 256, 0, stream>>>(cat16, 16, (const float*)nullptr, 0,
                                                   st16, conv_a_w, conv_a_b, a1);
  statsA_s8_kernel<<<256, 256, 0, stream>>>(a1, part, part2, 0);
  statsA_s1_kernel<<<256, 256, 0, stream>>>(plddt, part, part2, 8);
  statsB_kernel<<<9, 256, 0, stream>>>(part, part2, st9, 9, 9, 256, 256);
  conv_small_kernel<9,8><<<256, 256, 0, stream>>>(a1, 8, plddt, 1,
                                                  st9, conv_p_w, conv_p_b, alpha);
  agg_kernel2<<<256, 512, 0, stream>>>(alpha, z, v, agg);
  // out_transform (cat16 region is dead now; h1b/w1b reuse it)
  w1_prep<<<640, 256, 0, stream>>>(lin1_w, w1b);
  ln1_kernel<<<256, 256, 0, stream>>>(agg, ln1_g, ln1_b, h1b);
  gemm1_kernel<<<32, 256, 0, stream>>>(h1b, w1b, lin1_b, y);
  outB_kernel<<<32, 256, 0, stream>>>(y, x, ln2_g, ln2_b, lin2_w, lin2_b,
                                      lnf_g, lnf_b, xout);
  statsA_z_kernel<<<1024, 256, 0, stream>>>(z, part, part2);
  statsA_s8_kernel<<<256, 256, 0, stream>>>(alpha, part, part2, 128);
  statsB_kernel<<<136, 256, 0, stream>>>(part, part2, st136, 136, 128, 1024, 256);
  wz_prep2<<<90, 256, 0, stream>>>(conv_z_w, wzb2);
  conv_z3_kernel<<<512, 256, 0, stream>>>(z, alpha, st136, wzb2, conv_z_b, zout);
}